// Round 8
// baseline (14963.519 us; speedup 1.0000x reference)
//
#include <hip/hip_runtime.h>
#include <math.h>

typedef unsigned int u32;
typedef unsigned short u16;

#define EPS 1e-5f
#define PTS 64   // points per tile (= one wavefront)

// stats/scale-shift offsets into g_acc / g_st (floats)
#define S0 0
#define Q0 16
#define S1 32
#define Q1 96
#define S2 160
#define Q2 288
#define S3 416
#define Q3 672

__device__ float g_acc[1024];  // sums (S*) and sum-of-squares (Q*)
__device__ float g_st[1024];   // per-feature scale (at S*) and shift (at Q*)
__device__ int   g_is64;       // 1 if unq buffer is int64
__device__ int   g_inv64;      // 1 if unq_inv buffer is int64
__device__ int   g_umax;       // max(unq_inv)
__device__ long  g_U;          // segment count = g_umax + 1
__device__ int   g_xbf;        // 1 if pt_fea is packed bf16 (robustness)
__device__ int   g_wbf;        // 1 if weights/bn params are packed bf16

__device__ __forceinline__ float bf2f(u16 b){ return __uint_as_float(((u32)b) << 16); }
__device__ __forceinline__ u16 f2bf(float f){
  u32 u = __float_as_uint(f);
  return (u16)((u + 0x7fffu + ((u >> 16) & 1u)) >> 16);  // RNE
}

// generic float load honoring runtime format flag
__device__ __forceinline__ float ldf(const void* p, long i, int isbf){
  return isbf ? bf2f(((const u16*)p)[i]) : ((const float*)p)[i];
}

// float atomic max via sign-split HW atomics; requires init to -inf.
__device__ __forceinline__ void atomicMaxF32(float* addr, float v){
  if (v == 0.f) v = 0.f;            // canonicalize -0.0 -> +0.0
  if (v >= 0.f) atomicMax((int*)addr, __float_as_int(v));
  else          atomicMin((u32*)addr, __float_as_uint(v));
}

__device__ __forceinline__ void waveRed2(float& s, float& q){
  #pragma unroll
  for (int off = 32; off > 0; off >>= 1){
    s += __shfl_xor(s, off, 64);
    q += __shfl_xor(q, off, 64);
  }
}

// 16 outputs per call; inputs from LDS bf16 tile hsrc[FIN][PTS]
template<int FIN, int FOUT>
__device__ __forceinline__ void chunk16(const u16* hsrc, int lane,
    const void* W, const void* bias, int wbf, int j0, float acc[16])
{
  if (wbf){
    const u16* B  = (const u16*)bias;
    const u16* Wp = (const u16*)W;
    #pragma unroll
    for (int jj = 0; jj < 16; ++jj) acc[jj] = bf2f(B[j0 + jj]);
    #pragma unroll 4
    for (int k = 0; k < FIN; ++k){
      const float hk = bf2f(hsrc[k*PTS + lane]);
      const u16* Wr = Wp + (long)k*FOUT + j0;
      #pragma unroll
      for (int jj = 0; jj < 16; ++jj) acc[jj] = fmaf(hk, bf2f(Wr[jj]), acc[jj]);
    }
  } else {
    const float* B  = (const float*)bias;
    const float* Wp = (const float*)W;
    #pragma unroll
    for (int jj = 0; jj < 16; ++jj) acc[jj] = B[j0 + jj];
    #pragma unroll 4
    for (int k = 0; k < FIN; ++k){
      const float hk = bf2f(hsrc[k*PTS + lane]);
      const float* Wr = Wp + (long)k*FOUT + j0;
      #pragma unroll
      for (int jj = 0; jj < 16; ++jj) acc[jj] = fmaf(hk, Wr[jj], acc[jj]);
    }
  }
}

__device__ __forceinline__ void emitStats(float acc[16], bool valid, int lane, int j0,
                                          float* bs, float* bq){
  #pragma unroll
  for (int jj = 0; jj < 16; ++jj){
    float v = valid ? acc[jj] : 0.f;
    float s = v, q = v*v;
    waveRed2(s, q);
    if (lane == 0){ atomicAdd(&bs[j0+jj], s); atomicAdd(&bq[j0+jj], q); }
  }
}
__device__ __forceinline__ void emitH(float acc[16], int lane, int j0, int soff, int qoff, u16* hdst){
  #pragma unroll
  for (int jj = 0; jj < 16; ++jj){
    float z = fmaxf(acc[jj]*g_st[soff+j0+jj] + g_st[qoff+j0+jj], 0.f);
    hdst[(j0+jj)*PTS + lane] = f2bf(z);
  }
}

__global__ void kreset(){
  if (threadIdx.x == 0) g_umax = 0;
  for (int i = threadIdx.x; i < 1024; i += blockDim.x) g_acc[i] = 0.f;
}

// Format sniff (robustness; expected f32)
__global__ void ksniff_fmt(const u32* __restrict__ buf, long nElems, int which){
  __shared__ int cnt;
  if (threadIdx.x == 0) cnt = 0;
  __syncthreads();
  const long words = nElems/2 > 0 ? nElems/2 : 1;
  int c = 0;
  for (int r = 0; r < 4; ++r){
    long j = threadIdx.x + 256L*r;
    long i = (j * words) >> 10;
    if (i >= words) i = words - 1;
    u32 w = buf[i];
    int e = (w >> 7) & 0xFF;
    if (e >= 96 && e < 160) ++c;
  }
  atomicAdd(&cnt, c);
  __syncthreads();
  if (threadIdx.x == 0){
    int isbf = (cnt >= 717) ? 1 : 0;
    if (which == 0) g_xbf = isbf; else g_wbf = isbf;
  }
}

// int64 data (values < 2^31): all odd 32-bit words are zero. int32: not.
__global__ void ksniff_inv(const u32* __restrict__ w, long nwords){
  __shared__ int any;
  if (threadIdx.x == 0) any = 0;
  __syncthreads();
  for (long i = 2L*threadIdx.x + 1; i < nwords; i += 2L*blockDim.x){
    if (w[i] != 0u){ any = 1; break; }
  }
  __syncthreads();
  if (threadIdx.x == 0) g_inv64 = (any == 0) ? 1 : 0;
}

__global__ __launch_bounds__(256) void ksegU(const void* __restrict__ invv, int N){
  const int inv64 = g_inv64;
  int m = 0;
  const int stride = gridDim.x*blockDim.x;
  if (inv64){
    const long long* q = (const long long*)invv;
    for (int i = blockIdx.x*blockDim.x + threadIdx.x; i < N; i += stride)
      m = max(m, (int)q[i]);
  } else {
    const int* q = (const int*)invv;
    for (int i = blockIdx.x*blockDim.x + threadIdx.x; i < N; i += stride)
      m = max(m, q[i]);
  }
  #pragma unroll
  for (int off = 32; off > 0; off >>= 1) m = max(m, __shfl_xor(m, off, 64));
  if ((threadIdx.x & 63) == 0) atomicMax(&g_umax, m);
}

__global__ void ksetU(){
  if (threadIdx.x == 0) g_U = (long)g_umax + 1;
}

__global__ void ksniff_unq(const u32* __restrict__ w){
  const long nwords = 3L*g_U;
  __shared__ int any;
  if (threadIdx.x == 0) any = 0;
  __syncthreads();
  for (long i = 2L*threadIdx.x + 1; i < nwords; i += 2L*blockDim.x){
    if (w[i] != 0u){ any = 1; break; }
  }
  __syncthreads();
  if (threadIdx.x == 0) g_is64 = (any == 0) ? 1 : 0;
}

// init pooled region [3U, 131U) to -inf (f32)
__global__ void kpoolinit(float* __restrict__ out, long outSize){
  const long U = g_U;
  const long lo = 3*U;
  const long hi = (131*U < outSize) ? 131*U : outSize;
  const long i0 = (long)blockIdx.x*blockDim.x + threadIdx.x;
  const long stride = (long)gridDim.x*blockDim.x;
  for (long i = lo + i0; i < hi; i += stride) out[i] = -INFINITY;
}

// unq coords into [0, 3U) as f32
__global__ void kunq(float* __restrict__ out, const void* __restrict__ unqv, long outSize){
  const long U = g_U;
  const long n = (3*U < outSize) ? 3*U : outSize;
  const long i0 = (long)blockIdx.x*blockDim.x + threadIdx.x;
  const long stride = (long)gridDim.x*blockDim.x;
  if (g_is64){
    const long long* uq = (const long long*)unqv;
    for (long i = i0; i < n; i += stride) out[i] = (float)uq[i];
  } else {
    const int* uq = (const int*)unqv;
    for (long i = i0; i < n; i += stride) out[i] = (float)uq[i];
  }
}

__global__ __launch_bounds__(256) void kstats0(const void* __restrict__ x, int N){
  __shared__ float red[4][6];
  const int xbf = g_xbf;
  float s[3] = {0,0,0}, q[3] = {0,0,0};
  const int stride = gridDim.x*blockDim.x;
  for (int p = blockIdx.x*blockDim.x + threadIdx.x; p < N; p += stride){
    #pragma unroll
    for (int c = 0; c < 3; ++c){
      float v = ldf(x, (long)p*3 + c, xbf);
      s[c] += v; q[c] += v*v;
    }
  }
  #pragma unroll
  for (int c = 0; c < 3; ++c) waveRed2(s[c], q[c]);
  const int w = threadIdx.x >> 6, lane = threadIdx.x & 63;
  if (lane == 0){
    #pragma unroll
    for (int c = 0; c < 3; ++c){ red[w][c] = s[c]; red[w][3+c] = q[c]; }
  }
  __syncthreads();
  if (threadIdx.x < 6){
    float t = 0.f;
    #pragma unroll
    for (int k = 0; k < 4; ++k) t += red[k][threadIdx.x];
    const int c = threadIdx.x;
    atomicAdd(&g_acc[(c < 3) ? (S0 + c) : (Q0 + (c - 3))], t);
  }
}

__global__ void kfin(int dim, int soff, int qoff,
                     const void* __restrict__ g, const void* __restrict__ b, float invN){
  const int j = threadIdx.x;
  if (j >= dim) return;
  const int wbf = g_wbf;
  const float m = g_acc[soff+j]*invN;
  const float var = fmaxf(g_acc[qoff+j]*invN - m*m, 0.f);
  const float s = ldf(g, j, wbf)*rsqrtf(var + EPS);
  g_st[soff+j] = s;
  g_st[qoff+j] = ldf(b, j, wbf) - m*s;
}

// STAGE 1..3: stats for z1..z3; STAGE 4: final layer + segment-max (f32 out).
template<int STAGE>
__global__ __launch_bounds__(256) void kpass(
    const void* __restrict__ x, const void* __restrict__ unq_inv_v,
    const void* __restrict__ W1, const void* __restrict__ b1,
    const void* __restrict__ W2, const void* __restrict__ b2,
    const void* __restrict__ W3, const void* __restrict__ b3,
    const void* __restrict__ W4, const void* __restrict__ b4,
    float* __restrict__ out, int N, long outSize)
{
  constexpr bool NEED_H1 = (STAGE >= 2);
  constexpr bool NEED_H2 = (STAGE >= 3);
  constexpr bool NEED_H3 = (STAGE >= 4);
  __shared__ u16 h1s[NEED_H1 ?  64*PTS : 1];
  __shared__ u16 h2s[NEED_H2 ? 128*PTS : 1];
  __shared__ u16 h3s[NEED_H3 ? 256*PTS : 1];
  __shared__ float bs[(STAGE <= 3) ? 256 : 1], bq[(STAGE <= 3) ? 256 : 1];

  const long U = g_U;
  const int inv64 = g_inv64;
  const int xbf = g_xbf, wbf = g_wbf;
  const long loEl = 3*U;
  const long hiEl = (131*U < outSize) ? 131*U : outSize;

  const int tid  = threadIdx.x;
  const int w    = tid >> 6;
  const int lane = tid & 63;

  if constexpr (STAGE <= 3){
    for (int i = tid; i < 256; i += 256){ bs[i] = 0.f; bq[i] = 0.f; }
    __syncthreads();
  }

  const int nb = (N + PTS - 1) / PTS;
  for (int b = blockIdx.x; b < nb; b += gridDim.x){
    const int p = b*PTS + lane;
    const bool valid = p < N;

    { // bn0 + layer 1: 3 -> 64
      float h0[3];
      #pragma unroll
      for (int c = 0; c < 3; ++c){
        float xv = valid ? ldf(x, (long)p*3 + c, xbf) : 0.f;
        h0[c] = xv*g_st[S0 + c] + g_st[Q0 + c];
      }
      const int j0 = w*16;
      float acc[16];
      if (wbf){
        const u16* B = (const u16*)b1; const u16* Wp = (const u16*)W1;
        #pragma unroll
        for (int jj = 0; jj < 16; ++jj) acc[jj] = bf2f(B[j0 + jj]);
        #pragma unroll
        for (int k = 0; k < 3; ++k){
          const u16* Wr = Wp + k*64 + j0;
          #pragma unroll
          for (int jj = 0; jj < 16; ++jj) acc[jj] = fmaf(h0[k], bf2f(Wr[jj]), acc[jj]);
        }
      } else {
        const float* B = (const float*)b1; const float* Wp = (const float*)W1;
        #pragma unroll
        for (int jj = 0; jj < 16; ++jj) acc[jj] = B[j0 + jj];
        #pragma unroll
        for (int k = 0; k < 3; ++k){
          const float* Wr = Wp + k*64 + j0;
          #pragma unroll
          for (int jj = 0; jj < 16; ++jj) acc[jj] = fmaf(h0[k], Wr[jj], acc[jj]);
        }
      }
      if constexpr (STAGE == 1) emitStats(acc, valid, lane, j0, bs, bq);
      else                      emitH(acc, lane, j0, S1, Q1, h1s);
    }
    if constexpr (NEED_H1){ // layer 2: 64 -> 128
      __syncthreads();
      #pragma unroll
      for (int c = 0; c < 2; ++c){
        const int j0 = w*32 + c*16;
        float acc[16];
        chunk16<64,128>(h1s, lane, W2, b2, wbf, j0, acc);
        if constexpr (STAGE == 2) emitStats(acc, valid, lane, j0, bs, bq);
        else                      emitH(acc, lane, j0, S2, Q2, h2s);
      }
    }
    if constexpr (NEED_H2){ // layer 3: 128 -> 256
      __syncthreads();
      #pragma unroll
      for (int c = 0; c < 4; ++c){
        const int j0 = w*64 + c*16;
        float acc[16];
        chunk16<128,256>(h2s, lane, W3, b3, wbf, j0, acc);
        if constexpr (STAGE == 3) emitStats(acc, valid, lane, j0, bs, bq);
        else                      emitH(acc, lane, j0, S3, Q3, h3s);
      }
    }
    if constexpr (NEED_H3){ // layer 4: 256 -> 128, segment-max (f32)
      __syncthreads();
      long seg = -1;
      if (valid){
        if (inv64) seg = (long)((const long long*)unq_inv_v)[p];
        else       seg = (long)((const int*)unq_inv_v)[p];
      }
      const bool segok = valid && (seg >= 0) && (seg < U);
      const long rowbase = loEl + seg*128;
      #pragma unroll
      for (int c = 0; c < 2; ++c){
        const int j0 = w*32 + c*16;
        float acc[16];
        chunk16<256,128>(h3s, lane, W4, b4, wbf, j0, acc);
        if (segok){
          #pragma unroll
          for (int jj = 0; jj < 16; ++jj){
            const long e = rowbase + j0 + jj;
            if (e >= loEl && e < hiEl)
              atomicMaxF32(out + e, acc[jj]);
          }
        }
      }
    }
    __syncthreads();
  }

  if constexpr (STAGE <= 3){
    const int dim  = (STAGE == 1) ? 64 : (STAGE == 2) ? 128 : 256;
    const int soff = (STAGE == 1) ? S1 : (STAGE == 2) ? S2 : S3;
    const int qoff = (STAGE == 1) ? Q1 : (STAGE == 2) ? Q2 : Q3;
    for (int j = tid; j < dim; j += 256){
      atomicAdd(&g_acc[soff + j], bs[j]);
      atomicAdd(&g_acc[qoff + j], bq[j]);
    }
  }
}

extern "C" void kernel_launch(void* const* d_in, const int* in_sizes, int n_in,
                              void* d_out, int out_size, void* d_ws, size_t ws_size,
                              hipStream_t stream)
{
  const void* x       = d_in[0];
  const void* unq     = d_in[2];
  const void* unq_inv = d_in[3];
  const void* bn_g[4] = {d_in[4], d_in[6], d_in[8], d_in[10]};
  const void* bn_b[4] = {d_in[5], d_in[7], d_in[9], d_in[11]};
  const void* W1 = d_in[12]; const void* b1 = d_in[13];
  const void* W2 = d_in[14]; const void* b2 = d_in[15];
  const void* W3 = d_in[16]; const void* b3 = d_in[17];
  const void* W4 = d_in[18]; const void* b4 = d_in[19];

  const int N = in_sizes[0] / 3;
  float* out = (float*)d_out;
  const float invN = 1.0f / (float)N;
  const long outSize = (long)out_size;

  kreset<<<1, 1024, 0, stream>>>();
  ksniff_fmt<<<1, 256, 0, stream>>>((const u32*)x, (long)in_sizes[0], 0);
  ksniff_fmt<<<1, 256, 0, stream>>>((const u32*)W1, (long)in_sizes[12], 1);
  ksniff_inv<<<1, 1024, 0, stream>>>((const u32*)unq_inv, (long)N);
  ksegU<<<512, 256, 0, stream>>>(unq_inv, N);
  ksetU<<<1, 64, 0, stream>>>();
  ksniff_unq<<<1, 1024, 0, stream>>>((const u32*)unq);
  kpoolinit<<<2048, 256, 0, stream>>>(out, outSize);

  kstats0<<<1024, 256, 0, stream>>>(x, N);
  kfin<<<1, 256, 0, stream>>>(3, S0, Q0, bn_g[0], bn_b[0], invN);

  kpass<1><<<2048, 256, 0, stream>>>(x, unq_inv, W1,b1,W2,b2,W3,b3,W4,b4, out, N, outSize);
  kfin<<<1, 256, 0, stream>>>(64, S1, Q1, bn_g[1], bn_b[1], invN);

  kpass<2><<<2048, 256, 0, stream>>>(x, unq_inv, W1,b1,W2,b2,W3,b3,W4,b4, out, N, outSize);
  kfin<<<1, 256, 0, stream>>>(128, S2, Q2, bn_g[2], bn_b[2], invN);

  kpass<3><<<1024, 256, 0, stream>>>(x, unq_inv, W1,b1,W2,b2,W3,b3,W4,b4, out, N, outSize);
  kfin<<<1, 256, 0, stream>>>(256, S3, Q3, bn_g[3], bn_b[3], invN);

  kpass<4><<<1024, 256, 0, stream>>>(x, unq_inv, W1,b1,W2,b2,W3,b3,W4,b4, out, N, outSize);

  kunq<<<2048, 256, 0, stream>>>(out, unq, outSize);
}

// Round 9
// 13918.378 us; speedup vs baseline: 1.0751x; 1.0751x over previous
//
#include <hip/hip_runtime.h>
#include <math.h>

typedef unsigned int u32;
typedef unsigned short u16;

#define EPS 1e-5f
#define PTS 64   // points per tile (= one wavefront)

// stats/scale-shift offsets into g_acc / g_st (floats)
#define S0 0
#define Q0 16
#define S1 32
#define Q1 96
#define S2 160
#define Q2 288
#define S3 416
#define Q3 672

__device__ float g_acc[1024];  // sums (S*) and sum-of-squares (Q*)
__device__ float g_st[1024];   // per-feature scale (at S*) and shift (at Q*)
__device__ int   g_is64;       // 1 if unq buffer is int64
__device__ int   g_inv64;      // 1 if unq_inv buffer is int64
__device__ int   g_umax;       // max(unq_inv)
__device__ long  g_U;          // segment count = g_umax + 1
__device__ int   g_xbf;        // 1 if pt_fea is packed bf16 (robustness)
__device__ int   g_wbf;        // 1 if weights/bn params are packed bf16

__device__ __forceinline__ float bf2f(u16 b){ return __uint_as_float(((u32)b) << 16); }
__device__ __forceinline__ u16 f2bf(float f){
  u32 u = __float_as_uint(f);
  return (u16)((u + 0x7fffu + ((u >> 16) & 1u)) >> 16);  // RNE
}

// generic float load honoring runtime format flag
__device__ __forceinline__ float ldf(const void* p, long i, int isbf){
  return isbf ? bf2f(((const u16*)p)[i]) : ((const float*)p)[i];
}

// float atomic max via sign-split HW atomics; requires init to -inf.
__device__ __forceinline__ void atomicMaxF32(float* addr, float v){
  if (v == 0.f) v = 0.f;            // canonicalize -0.0 -> +0.0
  if (v >= 0.f) atomicMax((int*)addr, __float_as_int(v));
  else          atomicMin((u32*)addr, __float_as_uint(v));
}

__device__ __forceinline__ void waveRed2(float& s, float& q){
  #pragma unroll
  for (int off = 32; off > 0; off >>= 1){
    s += __shfl_xor(s, off, 64);
    q += __shfl_xor(q, off, 64);
  }
}

// 16 outputs per call; inputs from LDS bf16 tile hsrc[FIN][PTS].
// f32 weight path uses float4 loads (W row-major, j0 16-aligned).
template<int FIN, int FOUT>
__device__ __forceinline__ void chunk16(const u16* hsrc, int lane,
    const void* W, const void* bias, int wbf, int j0, float acc[16])
{
  if (wbf){
    const u16* B  = (const u16*)bias;
    const u16* Wp = (const u16*)W;
    #pragma unroll
    for (int jj = 0; jj < 16; ++jj) acc[jj] = bf2f(B[j0 + jj]);
    #pragma unroll 4
    for (int k = 0; k < FIN; ++k){
      const float hk = bf2f(hsrc[k*PTS + lane]);
      const u16* Wr = Wp + (long)k*FOUT + j0;
      #pragma unroll
      for (int jj = 0; jj < 16; ++jj) acc[jj] = fmaf(hk, bf2f(Wr[jj]), acc[jj]);
    }
  } else {
    const float* B  = (const float*)bias;
    const float* Wp = (const float*)W;
    #pragma unroll
    for (int jj = 0; jj < 16; ++jj) acc[jj] = B[j0 + jj];
    #pragma unroll 4
    for (int k = 0; k < FIN; ++k){
      const float hk = bf2f(hsrc[k*PTS + lane]);
      const float4* Wr = (const float4*)(Wp + (long)k*FOUT + j0);
      const float4 w0 = Wr[0], w1 = Wr[1], w2 = Wr[2], w3 = Wr[3];
      acc[ 0]=fmaf(hk,w0.x,acc[ 0]); acc[ 1]=fmaf(hk,w0.y,acc[ 1]);
      acc[ 2]=fmaf(hk,w0.z,acc[ 2]); acc[ 3]=fmaf(hk,w0.w,acc[ 3]);
      acc[ 4]=fmaf(hk,w1.x,acc[ 4]); acc[ 5]=fmaf(hk,w1.y,acc[ 5]);
      acc[ 6]=fmaf(hk,w1.z,acc[ 6]); acc[ 7]=fmaf(hk,w1.w,acc[ 7]);
      acc[ 8]=fmaf(hk,w2.x,acc[ 8]); acc[ 9]=fmaf(hk,w2.y,acc[ 9]);
      acc[10]=fmaf(hk,w2.z,acc[10]); acc[11]=fmaf(hk,w2.w,acc[11]);
      acc[12]=fmaf(hk,w3.x,acc[12]); acc[13]=fmaf(hk,w3.y,acc[13]);
      acc[14]=fmaf(hk,w3.z,acc[14]); acc[15]=fmaf(hk,w3.w,acc[15]);
    }
  }
}

__device__ __forceinline__ void emitStats(float acc[16], bool valid, int lane, int j0,
                                          float* bs, float* bq){
  #pragma unroll
  for (int jj = 0; jj < 16; ++jj){
    float v = valid ? acc[jj] : 0.f;
    float s = v, q = v*v;
    waveRed2(s, q);
    if (lane == 0){ atomicAdd(&bs[j0+jj], s); atomicAdd(&bq[j0+jj], q); }
  }
}
__device__ __forceinline__ void emitH(float acc[16], int lane, int j0, int soff, int qoff, u16* hdst){
  #pragma unroll
  for (int jj = 0; jj < 16; ++jj){
    float z = fmaxf(acc[jj]*g_st[soff+j0+jj] + g_st[qoff+j0+jj], 0.f);
    hdst[(j0+jj)*PTS + lane] = f2bf(z);
  }
}

__global__ void kreset(){
  if (threadIdx.x == 0) g_umax = 0;
  for (int i = threadIdx.x; i < 1024; i += blockDim.x) g_acc[i] = 0.f;
}

// Format sniff (robustness; expected f32)
__global__ void ksniff_fmt(const u32* __restrict__ buf, long nElems, int which){
  __shared__ int cnt;
  if (threadIdx.x == 0) cnt = 0;
  __syncthreads();
  const long words = nElems/2 > 0 ? nElems/2 : 1;
  int c = 0;
  for (int r = 0; r < 4; ++r){
    long j = threadIdx.x + 256L*r;
    long i = (j * words) >> 10;
    if (i >= words) i = words - 1;
    u32 w = buf[i];
    int e = (w >> 7) & 0xFF;
    if (e >= 96 && e < 160) ++c;
  }
  atomicAdd(&cnt, c);
  __syncthreads();
  if (threadIdx.x == 0){
    int isbf = (cnt >= 717) ? 1 : 0;
    if (which == 0) g_xbf = isbf; else g_wbf = isbf;
  }
}

// int64 data (values < 2^31): all odd 32-bit words are zero. int32: not.
__global__ void ksniff_inv(const u32* __restrict__ w, long nwords){
  __shared__ int any;
  if (threadIdx.x == 0) any = 0;
  __syncthreads();
  for (long i = 2L*threadIdx.x + 1; i < nwords; i += 2L*blockDim.x){
    if (w[i] != 0u){ any = 1; break; }
  }
  __syncthreads();
  if (threadIdx.x == 0) g_inv64 = (any == 0) ? 1 : 0;
}

__global__ __launch_bounds__(256) void ksegU(const void* __restrict__ invv, int N){
  const int inv64 = g_inv64;
  int m = 0;
  const int stride = gridDim.x*blockDim.x;
  if (inv64){
    const long long* q = (const long long*)invv;
    for (int i = blockIdx.x*blockDim.x + threadIdx.x; i < N; i += stride)
      m = max(m, (int)q[i]);
  } else {
    const int* q = (const int*)invv;
    for (int i = blockIdx.x*blockDim.x + threadIdx.x; i < N; i += stride)
      m = max(m, q[i]);
  }
  #pragma unroll
  for (int off = 32; off > 0; off >>= 1) m = max(m, __shfl_xor(m, off, 64));
  if ((threadIdx.x & 63) == 0) atomicMax(&g_umax, m);
}

__global__ void ksetU(){
  if (threadIdx.x == 0) g_U = (long)g_umax + 1;
}

__global__ void ksniff_unq(const u32* __restrict__ w){
  const long nwords = 3L*g_U;
  __shared__ int any;
  if (threadIdx.x == 0) any = 0;
  __syncthreads();
  for (long i = 2L*threadIdx.x + 1; i < nwords; i += 2L*blockDim.x){
    if (w[i] != 0u){ any = 1; break; }
  }
  __syncthreads();
  if (threadIdx.x == 0) g_is64 = (any == 0) ? 1 : 0;
}

// init pooled region [3U, 131U) to -inf (f32)
__global__ void kpoolinit(float* __restrict__ out, long outSize){
  const long U = g_U;
  const long lo = 3*U;
  const long hi = (131*U < outSize) ? 131*U : outSize;
  const long i0 = (long)blockIdx.x*blockDim.x + threadIdx.x;
  const long stride = (long)gridDim.x*blockDim.x;
  for (long i = lo + i0; i < hi; i += stride) out[i] = -INFINITY;
}

// unq coords into [0, 3U) as f32
__global__ void kunq(float* __restrict__ out, const void* __restrict__ unqv, long outSize){
  const long U = g_U;
  const long n = (3*U < outSize) ? 3*U : outSize;
  const long i0 = (long)blockIdx.x*blockDim.x + threadIdx.x;
  const long stride = (long)gridDim.x*blockDim.x;
  if (g_is64){
    const long long* uq = (const long long*)unqv;
    for (long i = i0; i < n; i += stride) out[i] = (float)uq[i];
  } else {
    const int* uq = (const int*)unqv;
    for (long i = i0; i < n; i += stride) out[i] = (float)uq[i];
  }
}

__global__ __launch_bounds__(256) void kstats0(const void* __restrict__ x, int N){
  __shared__ float red[4][6];
  const int xbf = g_xbf;
  float s[3] = {0,0,0}, q[3] = {0,0,0};
  const int stride = gridDim.x*blockDim.x;
  for (int p = blockIdx.x*blockDim.x + threadIdx.x; p < N; p += stride){
    #pragma unroll
    for (int c = 0; c < 3; ++c){
      float v = ldf(x, (long)p*3 + c, xbf);
      s[c] += v; q[c] += v*v;
    }
  }
  #pragma unroll
  for (int c = 0; c < 3; ++c) waveRed2(s[c], q[c]);
  const int w = threadIdx.x >> 6, lane = threadIdx.x & 63;
  if (lane == 0){
    #pragma unroll
    for (int c = 0; c < 3; ++c){ red[w][c] = s[c]; red[w][3+c] = q[c]; }
  }
  __syncthreads();
  if (threadIdx.x < 6){
    float t = 0.f;
    #pragma unroll
    for (int k = 0; k < 4; ++k) t += red[k][threadIdx.x];
    const int c = threadIdx.x;
    atomicAdd(&g_acc[(c < 3) ? (S0 + c) : (Q0 + (c - 3))], t);
  }
}

__global__ void kfin(int dim, int soff, int qoff,
                     const void* __restrict__ g, const void* __restrict__ b, float invN){
  const int j = threadIdx.x;
  if (j >= dim) return;
  const int wbf = g_wbf;
  const float m = g_acc[soff+j]*invN;
  const float var = fmaxf(g_acc[qoff+j]*invN - m*m, 0.f);
  const float s = ldf(g, j, wbf)*rsqrtf(var + EPS);
  g_st[soff+j] = s;
  g_st[qoff+j] = ldf(b, j, wbf) - m*s;
}

// STAGE 1..3: stats for z1..z3; STAGE 4: final layer + coalesced segment-max.
template<int STAGE>
__global__ __launch_bounds__(256) void kpass(
    const void* __restrict__ x, const void* __restrict__ unq_inv_v,
    const void* __restrict__ W1, const void* __restrict__ b1,
    const void* __restrict__ W2, const void* __restrict__ b2,
    const void* __restrict__ W3, const void* __restrict__ b3,
    const void* __restrict__ W4, const void* __restrict__ b4,
    float* __restrict__ out, int N, long outSize)
{
  constexpr bool NEED_H1 = (STAGE >= 2);
  constexpr bool NEED_H2 = (STAGE >= 3);
  constexpr bool NEED_H3 = (STAGE >= 4);
  constexpr int H1N = NEED_H1 ?  64*PTS : 1;
  constexpr int H2N = NEED_H2 ? 128*PTS : 1;
  constexpr int H3N = NEED_H3 ? 256*PTS : 1;
  constexpr int Z4R = NEED_H3 ? 64 : 1;

  // z4 staging reuses the h-tile space (h1..h3 dead by the time z4 is written)
  __shared__ union SU {
    struct { u16 h1[H1N]; u16 h2[H2N]; u16 h3[H3N]; } h;
    float z4[Z4R][132];   // padded stride (132) to spread LDS banks
  } sm;
  __shared__ float bs[(STAGE <= 3) ? 256 : 1], bq[(STAGE <= 3) ? 256 : 1];
  __shared__ int seg_s[NEED_H3 ? 64 : 1];

  const long U = g_U;
  const int inv64 = g_inv64;
  const int xbf = g_xbf, wbf = g_wbf;
  const long loEl = 3*U;
  const long hiEl = (131*U < outSize) ? 131*U : outSize;

  const int tid  = threadIdx.x;
  const int w    = tid >> 6;
  const int lane = tid & 63;

  if constexpr (STAGE <= 3){
    for (int i = tid; i < 256; i += 256){ bs[i] = 0.f; bq[i] = 0.f; }
    __syncthreads();
  }

  const int nb = (N + PTS - 1) / PTS;
  for (int b = blockIdx.x; b < nb; b += gridDim.x){
    const int p = b*PTS + lane;
    const bool valid = p < N;

    { // bn0 + layer 1: 3 -> 64
      float h0[3];
      #pragma unroll
      for (int c = 0; c < 3; ++c){
        float xv = valid ? ldf(x, (long)p*3 + c, xbf) : 0.f;
        h0[c] = xv*g_st[S0 + c] + g_st[Q0 + c];
      }
      const int j0 = w*16;
      float acc[16];
      if (wbf){
        const u16* B = (const u16*)b1; const u16* Wp = (const u16*)W1;
        #pragma unroll
        for (int jj = 0; jj < 16; ++jj) acc[jj] = bf2f(B[j0 + jj]);
        #pragma unroll
        for (int k = 0; k < 3; ++k){
          const u16* Wr = Wp + k*64 + j0;
          #pragma unroll
          for (int jj = 0; jj < 16; ++jj) acc[jj] = fmaf(h0[k], bf2f(Wr[jj]), acc[jj]);
        }
      } else {
        const float* B = (const float*)b1; const float* Wp = (const float*)W1;
        #pragma unroll
        for (int jj = 0; jj < 16; ++jj) acc[jj] = B[j0 + jj];
        #pragma unroll
        for (int k = 0; k < 3; ++k){
          const float* Wr = Wp + k*64 + j0;
          #pragma unroll
          for (int jj = 0; jj < 16; ++jj) acc[jj] = fmaf(h0[k], Wr[jj], acc[jj]);
        }
      }
      if constexpr (STAGE == 1) emitStats(acc, valid, lane, j0, bs, bq);
      else                      emitH(acc, lane, j0, S1, Q1, sm.h.h1);
    }
    if constexpr (NEED_H1){ // layer 2: 64 -> 128
      __syncthreads();
      #pragma unroll
      for (int c = 0; c < 2; ++c){
        const int j0 = w*32 + c*16;
        float acc[16];
        chunk16<64,128>(sm.h.h1, lane, W2, b2, wbf, j0, acc);
        if constexpr (STAGE == 2) emitStats(acc, valid, lane, j0, bs, bq);
        else                      emitH(acc, lane, j0, S2, Q2, sm.h.h2);
      }
    }
    if constexpr (NEED_H2){ // layer 3: 128 -> 256
      __syncthreads();
      #pragma unroll
      for (int c = 0; c < 4; ++c){
        const int j0 = w*64 + c*16;
        float acc[16];
        chunk16<128,256>(sm.h.h2, lane, W3, b3, wbf, j0, acc);
        if constexpr (STAGE == 3) emitStats(acc, valid, lane, j0, bs, bq);
        else                      emitH(acc, lane, j0, S3, Q3, sm.h.h3);
      }
    }
    if constexpr (NEED_H3){ // layer 4: 256 -> 128, staged + coalesced segment-max
      __syncthreads();  // h3 ready
      float accA[16], accB[16];
      chunk16<256,128>(sm.h.h3, lane, W4, b4, wbf, w*32,      accA);
      chunk16<256,128>(sm.h.h3, lane, W4, b4, wbf, w*32 + 16, accB);
      if (w == 0){
        long seg = -1;
        if (valid){
          if (inv64) seg = (long)((const long long*)unq_inv_v)[p];
          else       seg = (long)((const int*)unq_inv_v)[p];
        }
        seg_s[lane] = (seg >= 0 && seg < U &&
                       loEl + seg*128 + 128 <= hiEl) ? (int)seg : -1;
      }
      __syncthreads();  // all h3 reads done -> z4 space free; seg_s ready
      {
        float4* dst = (float4*)&sm.z4[lane][w*32];
        dst[0] = make_float4(accA[ 0],accA[ 1],accA[ 2],accA[ 3]);
        dst[1] = make_float4(accA[ 4],accA[ 5],accA[ 6],accA[ 7]);
        dst[2] = make_float4(accA[ 8],accA[ 9],accA[10],accA[11]);
        dst[3] = make_float4(accA[12],accA[13],accA[14],accA[15]);
        dst[4] = make_float4(accB[ 0],accB[ 1],accB[ 2],accB[ 3]);
        dst[5] = make_float4(accB[ 4],accB[ 5],accB[ 6],accB[ 7]);
        dst[6] = make_float4(accB[ 8],accB[ 9],accB[10],accB[11]);
        dst[7] = make_float4(accB[12],accB[13],accB[14],accB[15]);
      }
      __syncthreads();  // z4 complete
      // flush: 2 points per iteration; 128 consecutive lanes per point row
      #pragma unroll 4
      for (int pt2 = 0; pt2 < 64; pt2 += 2){
        const int pt = pt2 + (tid >> 7);
        const int f  = tid & 127;
        const int sg = seg_s[pt];
        if (sg >= 0)
          atomicMaxF32(out + loEl + (long)sg*128 + f, sm.z4[pt][f]);
      }
    }
    __syncthreads();  // protect LDS across tile iterations
  }

  if constexpr (STAGE <= 3){
    const int dim  = (STAGE == 1) ? 64 : (STAGE == 2) ? 128 : 256;
    const int soff = (STAGE == 1) ? S1 : (STAGE == 2) ? S2 : S3;
    const int qoff = (STAGE == 1) ? Q1 : (STAGE == 2) ? Q2 : Q3;
    for (int j = tid; j < dim; j += 256){
      atomicAdd(&g_acc[soff + j], bs[j]);
      atomicAdd(&g_acc[qoff + j], bq[j]);
    }
  }
}

extern "C" void kernel_launch(void* const* d_in, const int* in_sizes, int n_in,
                              void* d_out, int out_size, void* d_ws, size_t ws_size,
                              hipStream_t stream)
{
  const void* x       = d_in[0];
  const void* unq     = d_in[2];
  const void* unq_inv = d_in[3];
  const void* bn_g[4] = {d_in[4], d_in[6], d_in[8], d_in[10]};
  const void* bn_b[4] = {d_in[5], d_in[7], d_in[9], d_in[11]};
  const void* W1 = d_in[12]; const void* b1 = d_in[13];
  const void* W2 = d_in[14]; const void* b2 = d_in[15];
  const void* W3 = d_in[16]; const void* b3 = d_in[17];
  const void* W4 = d_in[18]; const void* b4 = d_in[19];

  const int N = in_sizes[0] / 3;
  float* out = (float*)d_out;
  const float invN = 1.0f / (float)N;
  const long outSize = (long)out_size;

  kreset<<<1, 1024, 0, stream>>>();
  ksniff_fmt<<<1, 256, 0, stream>>>((const u32*)x, (long)in_sizes[0], 0);
  ksniff_fmt<<<1, 256, 0, stream>>>((const u32*)W1, (long)in_sizes[12], 1);
  ksniff_inv<<<1, 1024, 0, stream>>>((const u32*)unq_inv, (long)N);
  ksegU<<<512, 256, 0, stream>>>(unq_inv, N);
  ksetU<<<1, 64, 0, stream>>>();
  ksniff_unq<<<1, 1024, 0, stream>>>((const u32*)unq);
  kpoolinit<<<2048, 256, 0, stream>>>(out, outSize);

  kstats0<<<1024, 256, 0, stream>>>(x, N);
  kfin<<<1, 256, 0, stream>>>(3, S0, Q0, bn_g[0], bn_b[0], invN);

  kpass<1><<<2048, 256, 0, stream>>>(x, unq_inv, W1,b1,W2,b2,W3,b3,W4,b4, out, N, outSize);
  kfin<<<1, 256, 0, stream>>>(64, S1, Q1, bn_g[1], bn_b[1], invN);

  kpass<2><<<2048, 256, 0, stream>>>(x, unq_inv, W1,b1,W2,b2,W3,b3,W4,b4, out, N, outSize);
  kfin<<<1, 256, 0, stream>>>(128, S2, Q2, bn_g[2], bn_b[2], invN);

  kpass<3><<<1024, 256, 0, stream>>>(x, unq_inv, W1,b1,W2,b2,W3,b3,W4,b4, out, N, outSize);
  kfin<<<1, 256, 0, stream>>>(256, S3, Q3, bn_g[3], bn_b[3], invN);

  kpass<4><<<1024, 256, 0, stream>>>(x, unq_inv, W1,b1,W2,b2,W3,b3,W4,b4, out, N, outSize);

  kunq<<<2048, 256, 0, stream>>>(out, unq, outSize);
}

// Round 10
// 3939.963 us; speedup vs baseline: 3.7979x; 3.5326x over previous
//
#include <hip/hip_runtime.h>
#include <math.h>

typedef unsigned int u32;
typedef unsigned short u16;

#define EPS 1e-5f
#define PTS 64   // points per tile (= one wavefront)

// stats/scale-shift offsets into g_acc / g_st (floats)
#define S0 0
#define Q0 16
#define S1 32
#define Q1 96
#define S2 160
#define Q2 288
#define S3 416
#define Q3 672

__device__ float g_acc[1024];  // sums (S*), sum-of-squares (Q*), cross-terms (Q0+3..5)
__device__ float g_st[1024];   // per-feature scale (at S*) and shift (at Q*)
__device__ int   g_is64;       // 1 if unq buffer is int64
__device__ int   g_inv64;      // 1 if unq_inv buffer is int64
__device__ int   g_umax;       // max(unq_inv)
__device__ long  g_U;          // segment count = g_umax + 1

__device__ __forceinline__ float bf2f(u16 b){ return __uint_as_float(((u32)b) << 16); }
__device__ __forceinline__ u16 f2bf(float f){
  u32 u = __float_as_uint(f);
  return (u16)((u + 0x7fffu + ((u >> 16) & 1u)) >> 16);  // RNE
}

// float atomic max via sign-split HW atomics; requires init to -inf.
__device__ __forceinline__ void atomicMaxF32(float* addr, float v){
  if (v == 0.f) v = 0.f;            // canonicalize -0.0 -> +0.0
  if (v >= 0.f) atomicMax((int*)addr, __float_as_int(v));
  else          atomicMin((u32*)addr, __float_as_uint(v));
}

__device__ __forceinline__ void waveRedArr(float* v, int n){
  #pragma unroll
  for (int off = 32; off > 0; off >>= 1)
    for (int i = 0; i < n; ++i) v[i] += __shfl_xor(v[i], off, 64);
}

// 16 outputs; h from LDS bf16 tile hsrc[FIN][PTS]; weights via wave-uniform
// (readfirstlane-forced) scalar addressing -> s_load expected.
template<int FIN, int FOUT>
__device__ __forceinline__ void chunk16(const u16* hsrc, int lane,
    const float* __restrict__ W, const float* __restrict__ bias,
    int j0, float acc[16])
{
  const int j0u = __builtin_amdgcn_readfirstlane(j0);
  #pragma unroll
  for (int jj = 0; jj < 16; ++jj) acc[jj] = bias[j0u + jj];
  #pragma unroll 4
  for (int k = 0; k < FIN; ++k){
    const float hk = bf2f(hsrc[k*PTS + lane]);
    const float* Wr = W + (long)k*FOUT + j0u;
    #pragma unroll
    for (int jj = 0; jj < 16; ++jj) acc[jj] = fmaf(hk, Wr[jj], acc[jj]);
  }
}

__device__ __forceinline__ void emitStats(float acc[16], bool valid, int lane, int j0,
                                          float* bs, float* bq){
  #pragma unroll
  for (int jj = 0; jj < 16; ++jj){
    float v = valid ? acc[jj] : 0.f;
    float sq[2] = {v, v*v};
    waveRedArr(sq, 2);
    if (lane == 0){ atomicAdd(&bs[j0+jj], sq[0]); atomicAdd(&bq[j0+jj], sq[1]); }
  }
}
__device__ __forceinline__ void emitH(float acc[16], int lane, int j0u, int soff, int qoff, u16* hdst){
  #pragma unroll
  for (int jj = 0; jj < 16; ++jj){
    float z = fmaxf(acc[jj]*g_st[soff+j0u+jj] + g_st[qoff+j0u+jj], 0.f);
    hdst[(j0u+jj)*PTS + lane] = f2bf(z);
  }
}

__global__ void kreset(){
  if (threadIdx.x == 0) g_umax = 0;
  for (int i = threadIdx.x; i < 1024; i += blockDim.x) g_acc[i] = 0.f;
}

// int64 data (values < 2^31): all odd 32-bit words are zero. int32: not.
__global__ void ksniff_inv(const u32* __restrict__ w, long nwords){
  __shared__ int any;
  if (threadIdx.x == 0) any = 0;
  __syncthreads();
  for (long i = 2L*threadIdx.x + 1; i < nwords; i += 2L*blockDim.x){
    if (w[i] != 0u){ any = 1; break; }
  }
  __syncthreads();
  if (threadIdx.x == 0) g_inv64 = (any == 0) ? 1 : 0;
}

__global__ __launch_bounds__(256) void ksegU(const void* __restrict__ invv, int N){
  const int inv64 = g_inv64;
  int m = 0;
  const int stride = gridDim.x*blockDim.x;
  if (inv64){
    const long long* q = (const long long*)invv;
    for (int i = blockIdx.x*blockDim.x + threadIdx.x; i < N; i += stride)
      m = max(m, (int)q[i]);
  } else {
    const int* q = (const int*)invv;
    for (int i = blockIdx.x*blockDim.x + threadIdx.x; i < N; i += stride)
      m = max(m, q[i]);
  }
  #pragma unroll
  for (int off = 32; off > 0; off >>= 1) m = max(m, __shfl_xor(m, off, 64));
  if ((threadIdx.x & 63) == 0) atomicMax(&g_umax, m);
}

__global__ void ksetU(){
  if (threadIdx.x == 0) g_U = (long)g_umax + 1;
}

__global__ void ksniff_unq(const u32* __restrict__ w){
  const long nwords = 3L*g_U;
  __shared__ int any;
  if (threadIdx.x == 0) any = 0;
  __syncthreads();
  for (long i = 2L*threadIdx.x + 1; i < nwords; i += 2L*blockDim.x){
    if (w[i] != 0u){ any = 1; break; }
  }
  __syncthreads();
  if (threadIdx.x == 0) g_is64 = (any == 0) ? 1 : 0;
}

// init pooled region [3U, 131U) to -inf (f32)
__global__ void kpoolinit(float* __restrict__ out, long outSize){
  const long U = g_U;
  const long lo = 3*U;
  const long hi = (131*U < outSize) ? 131*U : outSize;
  const long i0 = (long)blockIdx.x*blockDim.x + threadIdx.x;
  const long stride = (long)gridDim.x*blockDim.x;
  for (long i = lo + i0; i < hi; i += stride) out[i] = -INFINITY;
}

// unq coords into [0, 3U) as f32
__global__ void kunq(float* __restrict__ out, const void* __restrict__ unqv, long outSize){
  const long U = g_U;
  const long n = (3*U < outSize) ? 3*U : outSize;
  const long i0 = (long)blockIdx.x*blockDim.x + threadIdx.x;
  const long stride = (long)gridDim.x*blockDim.x;
  if (g_is64){
    const long long* uq = (const long long*)unqv;
    for (long i = i0; i < n; i += stride) out[i] = (float)uq[i];
  } else {
    const int* uq = (const int*)unqv;
    for (long i = i0; i < n; i += stride) out[i] = (float)uq[i];
  }
}

// stats0: 9 sums over x: Σx (3), Σx² (3), Σxy,Σxz,Σyz (3)
__global__ __launch_bounds__(256) void kstats0(const float* __restrict__ x, int N){
  __shared__ float red[4][9];
  float a[9];
  #pragma unroll
  for (int i = 0; i < 9; ++i) a[i] = 0.f;
  const int stride = gridDim.x*blockDim.x;
  for (int p = blockIdx.x*blockDim.x + threadIdx.x; p < N; p += stride){
    float v0 = x[(size_t)p*3 + 0], v1 = x[(size_t)p*3 + 1], v2 = x[(size_t)p*3 + 2];
    a[0]+=v0; a[1]+=v1; a[2]+=v2;
    a[3]+=v0*v0; a[4]+=v1*v1; a[5]+=v2*v2;
    a[6]+=v0*v1; a[7]+=v0*v2; a[8]+=v1*v2;
  }
  waveRedArr(a, 9);
  const int w = threadIdx.x >> 6, lane = threadIdx.x & 63;
  if (lane == 0){
    #pragma unroll
    for (int i = 0; i < 9; ++i) red[w][i] = a[i];
  }
  __syncthreads();
  if (threadIdx.x < 9){
    float t = 0.f;
    #pragma unroll
    for (int k = 0; k < 4; ++k) t += red[k][threadIdx.x];
    const int c = threadIdx.x;
    atomicAdd(&g_acc[(c < 3) ? (S0 + c) : (Q0 + (c - 3))], t);
  }
}

// generic BN finalize from accumulated stats (BN0, BN2, BN3)
__global__ void kfin(int dim, int soff, int qoff,
                     const float* __restrict__ g, const float* __restrict__ b, float invN){
  const int j = threadIdx.x;
  if (j >= dim) return;
  const float m = g_acc[soff+j]*invN;
  const float var = fmaxf(g_acc[qoff+j]*invN - m*m, 0.f);
  const float s = g[j]*rsqrtf(var + EPS);
  g_st[soff+j] = s;
  g_st[qoff+j] = b[j] - m*s;
}

// analytic BN1 finalize: z1 = bn0(x)@W1 + b1 is affine in bn0(x) = x*s0 + t0.
// mean(z1_j) = Σ_c (m0_c s0_c + t0_c) W1[c,j] + b1_j
// var(z1_j)  = Σ_{a,b} W1[a,j] W1[b,j] s0_a s0_b Cov(x)_{ab}
__global__ void kfin1(const float* __restrict__ g1, const float* __restrict__ b1bn,
                      const float* __restrict__ W1, const float* __restrict__ b1lin,
                      float invN){
  const int j = threadIdx.x;
  if (j >= 64) return;
  float m0[3], s0[3], t0[3];
  #pragma unroll
  for (int c = 0; c < 3; ++c){
    m0[c] = g_acc[S0+c]*invN;
    s0[c] = g_st[S0+c];
    t0[c] = g_st[Q0+c];
  }
  float C[3][3];
  C[0][0] = g_acc[Q0+0]*invN - m0[0]*m0[0];
  C[1][1] = g_acc[Q0+1]*invN - m0[1]*m0[1];
  C[2][2] = g_acc[Q0+2]*invN - m0[2]*m0[2];
  C[0][1] = C[1][0] = g_acc[Q0+3]*invN - m0[0]*m0[1];
  C[0][2] = C[2][0] = g_acc[Q0+4]*invN - m0[0]*m0[2];
  C[1][2] = C[2][1] = g_acc[Q0+5]*invN - m0[1]*m0[2];

  float wj[3] = {W1[0*64 + j], W1[1*64 + j], W1[2*64 + j]};
  float mean = b1lin[j];
  #pragma unroll
  for (int c = 0; c < 3; ++c) mean += (m0[c]*s0[c] + t0[c])*wj[c];
  float var = 0.f;
  #pragma unroll
  for (int a = 0; a < 3; ++a)
    #pragma unroll
    for (int b = 0; b < 3; ++b)
      var += wj[a]*s0[a]*wj[b]*s0[b]*C[a][b];
  var = fmaxf(var, 0.f);
  const float sc = g1[j]*rsqrtf(var + EPS);
  g_st[S1+j] = sc;
  g_st[Q1+j] = b1bn[j] - mean*sc;
}

// STAGE 2..3: stats for z2..z3; STAGE 4: final layer + coalesced segment-max.
template<int STAGE>
__global__ __launch_bounds__(256) void kpass(
    const float* __restrict__ x, const void* __restrict__ unq_inv_v,
    const float* __restrict__ W1, const float* __restrict__ b1,
    const float* __restrict__ W2, const float* __restrict__ b2,
    const float* __restrict__ W3, const float* __restrict__ b3,
    const float* __restrict__ W4, const float* __restrict__ b4,
    float* __restrict__ out, int N, long outSize)
{
  constexpr bool NEED_H2 = (STAGE >= 3);
  constexpr bool NEED_H3 = (STAGE >= 4);
  constexpr int H1N = 64*PTS;
  constexpr int H2N = NEED_H2 ? 128*PTS : 1;
  constexpr int H3N = NEED_H3 ? 256*PTS : 1;
  constexpr int Z4R = NEED_H3 ? 64 : 1;

  __shared__ union SU {
    struct { u16 h1[H1N]; u16 h2[H2N]; u16 h3[H3N]; } h;
    float z4[Z4R][132];   // padded stride to spread LDS banks
  } sm;
  __shared__ float bs[(STAGE <= 3) ? 256 : 1], bq[(STAGE <= 3) ? 256 : 1];
  __shared__ int seg_s[NEED_H3 ? 64 : 1];

  const long U = g_U;
  const int inv64 = g_inv64;
  const long loEl = 3*U;
  const long hiEl = (131*U < outSize) ? 131*U : outSize;

  const int tid  = threadIdx.x;
  const int w    = tid >> 6;
  const int lane = tid & 63;

  if constexpr (STAGE <= 3){
    for (int i = tid; i < 256; i += 256){ bs[i] = 0.f; bq[i] = 0.f; }
    __syncthreads();
  }

  const int nb = (N + PTS - 1) / PTS;
  for (int b = blockIdx.x; b < nb; b += gridDim.x){
    const int p = b*PTS + lane;
    const bool valid = p < N;

    { // bn0 + layer 1: 3 -> 64 (always needed; feeds h1)
      float h0[3];
      #pragma unroll
      for (int c = 0; c < 3; ++c){
        float xv = valid ? x[(size_t)p*3 + c] : 0.f;
        h0[c] = xv*g_st[S0 + c] + g_st[Q0 + c];
      }
      const int j0u = __builtin_amdgcn_readfirstlane(w*16);
      float acc[16];
      #pragma unroll
      for (int jj = 0; jj < 16; ++jj) acc[jj] = b1[j0u + jj];
      #pragma unroll
      for (int k = 0; k < 3; ++k){
        const float* Wr = W1 + k*64 + j0u;
        #pragma unroll
        for (int jj = 0; jj < 16; ++jj) acc[jj] = fmaf(h0[k], Wr[jj], acc[jj]);
      }
      emitH(acc, lane, j0u, S1, Q1, sm.h.h1);
    }
    { // layer 2: 64 -> 128
      __syncthreads();
      #pragma unroll
      for (int c = 0; c < 2; ++c){
        const int j0 = w*32 + c*16;
        float acc[16];
        chunk16<64,128>(sm.h.h1, lane, W2, b2, j0, acc);
        if constexpr (STAGE == 2) emitStats(acc, valid, lane, j0, bs, bq);
        else emitH(acc, lane, __builtin_amdgcn_readfirstlane(j0), S2, Q2, sm.h.h2);
      }
    }
    if constexpr (NEED_H2){ // layer 3: 128 -> 256
      __syncthreads();
      #pragma unroll
      for (int c = 0; c < 4; ++c){
        const int j0 = w*64 + c*16;
        float acc[16];
        chunk16<128,256>(sm.h.h2, lane, W3, b3, j0, acc);
        if constexpr (STAGE == 3) emitStats(acc, valid, lane, j0, bs, bq);
        else emitH(acc, lane, __builtin_amdgcn_readfirstlane(j0), S3, Q3, sm.h.h3);
      }
    }
    if constexpr (NEED_H3){ // layer 4: 256 -> 128, staged + coalesced segment-max
      __syncthreads();  // h3 ready
      float accA[16], accB[16];
      chunk16<256,128>(sm.h.h3, lane, W4, b4, w*32,      accA);
      chunk16<256,128>(sm.h.h3, lane, W4, b4, w*32 + 16, accB);
      if (w == 0){
        long seg = -1;
        if (valid){
          if (inv64) seg = (long)((const long long*)unq_inv_v)[p];
          else       seg = (long)((const int*)unq_inv_v)[p];
        }
        seg_s[lane] = (seg >= 0 && seg < U &&
                       loEl + seg*128 + 128 <= hiEl) ? (int)seg : -1;
      }
      __syncthreads();  // all h3 reads done -> z4 space free; seg_s ready
      {
        float4* dst = (float4*)&sm.z4[lane][w*32];
        dst[0] = make_float4(accA[ 0],accA[ 1],accA[ 2],accA[ 3]);
        dst[1] = make_float4(accA[ 4],accA[ 5],accA[ 6],accA[ 7]);
        dst[2] = make_float4(accA[ 8],accA[ 9],accA[10],accA[11]);
        dst[3] = make_float4(accA[12],accA[13],accA[14],accA[15]);
        dst[4] = make_float4(accB[ 0],accB[ 1],accB[ 2],accB[ 3]);
        dst[5] = make_float4(accB[ 4],accB[ 5],accB[ 6],accB[ 7]);
        dst[6] = make_float4(accB[ 8],accB[ 9],accB[10],accB[11]);
        dst[7] = make_float4(accB[12],accB[13],accB[14],accB[15]);
      }
      __syncthreads();  // z4 complete
      #pragma unroll 4
      for (int pt2 = 0; pt2 < 64; pt2 += 2){
        const int pt = pt2 + (tid >> 7);
        const int f  = tid & 127;
        const int sg = seg_s[pt];
        if (sg >= 0)
          atomicMaxF32(out + loEl + (long)sg*128 + f, sm.z4[pt][f]);
      }
    }
    __syncthreads();  // protect LDS across tile iterations
  }

  if constexpr (STAGE <= 3){
    const int dim  = (STAGE == 2) ? 128 : 256;
    const int soff = (STAGE == 2) ? S2 : S3;
    const int qoff = (STAGE == 2) ? Q2 : Q3;
    for (int j = tid; j < dim; j += 256){
      atomicAdd(&g_acc[soff + j], bs[j]);
      atomicAdd(&g_acc[qoff + j], bq[j]);
    }
  }
}

extern "C" void kernel_launch(void* const* d_in, const int* in_sizes, int n_in,
                              void* d_out, int out_size, void* d_ws, size_t ws_size,
                              hipStream_t stream)
{
  const float* x       = (const float*)d_in[0];
  const void*  unq     = d_in[2];
  const void*  unq_inv = d_in[3];
  const float* bn_g[4] = {(const float*)d_in[4], (const float*)d_in[6], (const float*)d_in[8], (const float*)d_in[10]};
  const float* bn_b[4] = {(const float*)d_in[5], (const float*)d_in[7], (const float*)d_in[9], (const float*)d_in[11]};
  const float* W1 = (const float*)d_in[12]; const float* b1 = (const float*)d_in[13];
  const float* W2 = (const float*)d_in[14]; const float* b2 = (const float*)d_in[15];
  const float* W3 = (const float*)d_in[16]; const float* b3 = (const float*)d_in[17];
  const float* W4 = (const float*)d_in[18]; const float* b4 = (const float*)d_in[19];

  const int N = in_sizes[0] / 3;
  float* out = (float*)d_out;
  const float invN = 1.0f / (float)N;
  const long outSize = (long)out_size;

  kreset<<<1, 1024, 0, stream>>>();
  ksniff_inv<<<1, 1024, 0, stream>>>((const u32*)unq_inv, (long)N);
  ksegU<<<512, 256, 0, stream>>>(unq_inv, N);
  ksetU<<<1, 64, 0, stream>>>();
  ksniff_unq<<<1, 1024, 0, stream>>>((const u32*)unq);
  kpoolinit<<<2048, 256, 0, stream>>>(out, outSize);

  kstats0<<<1024, 256, 0, stream>>>(x, N);
  kfin<<<1, 256, 0, stream>>>(3, S0, Q0, bn_g[0], bn_b[0], invN);
  kfin1<<<1, 64, 0, stream>>>(bn_g[1], bn_b[1], W1, b1, invN);   // analytic BN1 (pass 1 eliminated)

  kpass<2><<<1024, 256, 0, stream>>>(x, unq_inv, W1,b1,W2,b2,W3,b3,W4,b4, out, N, outSize);
  kfin<<<1, 256, 0, stream>>>(128, S2, Q2, bn_g[2], bn_b[2], invN);

  kpass<3><<<1024, 256, 0, stream>>>(x, unq_inv, W1,b1,W2,b2,W3,b3,W4,b4, out, N, outSize);
  kfin<<<1, 256, 0, stream>>>(256, S3, Q3, bn_g[3], bn_b[3], invN);

  kpass<4><<<1024, 256, 0, stream>>>(x, unq_inv, W1,b1,W2,b2,W3,b3,W4,b4, out, N, outSize);

  kunq<<<2048, 256, 0, stream>>>(out, unq, outSize);
}

// Round 11
// 3661.241 us; speedup vs baseline: 4.0870x; 1.0761x over previous
//
#include <hip/hip_runtime.h>
#include <math.h>

typedef unsigned int u32;
typedef unsigned short u16;

#define EPS 1e-5f
#define PTS 64   // points per tile (= one wavefront)

// stats/scale-shift offsets into g_acc / g_st (floats)
#define S0 0
#define Q0 16
#define S1 32
#define Q1 96
#define S2 160
#define Q2 288
#define S3 416
#define Q3 672

__device__ float g_acc[1024];  // sums (S*), sum-of-squares (Q*), cross-terms (Q0+3..5)
__device__ float g_st[1024];   // per-feature scale (at S*) and shift (at Q*)
__device__ int   g_is64;       // 1 if unq buffer is int64
__device__ int   g_inv64;      // 1 if unq_inv buffer is int64
__device__ int   g_umax;       // max(unq_inv)
__device__ long  g_U;          // segment count = g_umax + 1

__device__ __forceinline__ float bf2f(u16 b){ return __uint_as_float(((u32)b) << 16); }
__device__ __forceinline__ u16 f2bf(float f){
  u32 u = __float_as_uint(f);
  return (u16)((u + 0x7fffu + ((u >> 16) & 1u)) >> 16);  // RNE
}

// float atomic max via sign-split HW atomics; requires init to -inf.
__device__ __forceinline__ void atomicMaxF32(float* addr, float v){
  if (v == 0.f) v = 0.f;            // canonicalize -0.0 -> +0.0
  if (v >= 0.f) atomicMax((int*)addr, __float_as_int(v));
  else          atomicMin((u32*)addr, __float_as_uint(v));
}

__device__ __forceinline__ void waveRedArr(float* v, int n){
  #pragma unroll
  for (int off = 32; off > 0; off >>= 1)
    for (int i = 0; i < n; ++i) v[i] += __shfl_xor(v[i], off, 64);
}

// 16 outputs; h from LDS bf16 tile hsrc[FIN][PTS]; weights via wave-uniform
// (readfirstlane-forced) scalar addressing -> s_load.
template<int FIN, int FOUT>
__device__ __forceinline__ void chunk16(const u16* hsrc, int lane,
    const float* __restrict__ W, const float* __restrict__ bias,
    int j0, float acc[16])
{
  const int j0u = __builtin_amdgcn_readfirstlane(j0);
  #pragma unroll
  for (int jj = 0; jj < 16; ++jj) acc[jj] = bias[j0u + jj];
  #pragma unroll 4
  for (int k = 0; k < FIN; ++k){
    const float hk = bf2f(hsrc[k*PTS + lane]);
    const float* Wr = W + (long)k*FOUT + j0u;
    #pragma unroll
    for (int jj = 0; jj < 16; ++jj) acc[jj] = fmaf(hk, Wr[jj], acc[jj]);
  }
}

__device__ __forceinline__ void emitStats(float acc[16], bool valid, int lane, int j0,
                                          float* bs, float* bq){
  #pragma unroll
  for (int jj = 0; jj < 16; ++jj){
    float v = valid ? acc[jj] : 0.f;
    float sq[2] = {v, v*v};
    waveRedArr(sq, 2);
    if (lane == 0){ atomicAdd(&bs[j0+jj], sq[0]); atomicAdd(&bq[j0+jj], sq[1]); }
  }
}
__device__ __forceinline__ void emitH(float acc[16], int lane, int j0u, int soff, int qoff, u16* hdst){
  #pragma unroll
  for (int jj = 0; jj < 16; ++jj){
    float z = fmaxf(acc[jj]*g_st[soff+j0u+jj] + g_st[qoff+j0u+jj], 0.f);
    hdst[(j0u+jj)*PTS + lane] = f2bf(z);
  }
}

__global__ void kreset(){
  if (threadIdx.x == 0) g_umax = 0;
  for (int i = threadIdx.x; i < 1024; i += blockDim.x) g_acc[i] = 0.f;
}

// int64 data (values < 2^31): all odd 32-bit words are zero. int32: not.
__global__ void ksniff_inv(const u32* __restrict__ w, long nwords){
  __shared__ int any;
  if (threadIdx.x == 0) any = 0;
  __syncthreads();
  for (long i = 2L*threadIdx.x + 1; i < nwords; i += 2L*blockDim.x){
    if (w[i] != 0u){ any = 1; break; }
  }
  __syncthreads();
  if (threadIdx.x == 0) g_inv64 = (any == 0) ? 1 : 0;
}

__global__ __launch_bounds__(256) void ksegU(const void* __restrict__ invv, int N){
  const int inv64 = g_inv64;
  int m = 0;
  const int stride = gridDim.x*blockDim.x;
  if (inv64){
    const long long* q = (const long long*)invv;
    for (int i = blockIdx.x*blockDim.x + threadIdx.x; i < N; i += stride)
      m = max(m, (int)q[i]);
  } else {
    const int* q = (const int*)invv;
    for (int i = blockIdx.x*blockDim.x + threadIdx.x; i < N; i += stride)
      m = max(m, q[i]);
  }
  #pragma unroll
  for (int off = 32; off > 0; off >>= 1) m = max(m, __shfl_xor(m, off, 64));
  if ((threadIdx.x & 63) == 0) atomicMax(&g_umax, m);
}

__global__ void ksetU(){
  if (threadIdx.x == 0) g_U = (long)g_umax + 1;
}

__global__ void ksniff_unq(const u32* __restrict__ w){
  const long nwords = 3L*g_U;
  __shared__ int any;
  if (threadIdx.x == 0) any = 0;
  __syncthreads();
  for (long i = 2L*threadIdx.x + 1; i < nwords; i += 2L*blockDim.x){
    if (w[i] != 0u){ any = 1; break; }
  }
  __syncthreads();
  if (threadIdx.x == 0) g_is64 = (any == 0) ? 1 : 0;
}

// init pooled region [3U, 131U) to -inf (f32)
__global__ void kpoolinit(float* __restrict__ out, long outSize){
  const long U = g_U;
  const long lo = 3*U;
  const long hi = (131*U < outSize) ? 131*U : outSize;
  const long i0 = (long)blockIdx.x*blockDim.x + threadIdx.x;
  const long stride = (long)gridDim.x*blockDim.x;
  for (long i = lo + i0; i < hi; i += stride) out[i] = -INFINITY;
}

// unq coords into [0, 3U) as f32
__global__ void kunq(float* __restrict__ out, const void* __restrict__ unqv, long outSize){
  const long U = g_U;
  const long n = (3*U < outSize) ? 3*U : outSize;
  const long i0 = (long)blockIdx.x*blockDim.x + threadIdx.x;
  const long stride = (long)gridDim.x*blockDim.x;
  if (g_is64){
    const long long* uq = (const long long*)unqv;
    for (long i = i0; i < n; i += stride) out[i] = (float)uq[i];
  } else {
    const int* uq = (const int*)unqv;
    for (long i = i0; i < n; i += stride) out[i] = (float)uq[i];
  }
}

// stats0: 9 sums over x: Σx (3), Σx² (3), Σxy,Σxz,Σyz (3)
__global__ __launch_bounds__(256) void kstats0(const float* __restrict__ x, int N){
  __shared__ float red[4][9];
  float a[9];
  #pragma unroll
  for (int i = 0; i < 9; ++i) a[i] = 0.f;
  const int stride = gridDim.x*blockDim.x;
  for (int p = blockIdx.x*blockDim.x + threadIdx.x; p < N; p += stride){
    float v0 = x[(size_t)p*3 + 0], v1 = x[(size_t)p*3 + 1], v2 = x[(size_t)p*3 + 2];
    a[0]+=v0; a[1]+=v1; a[2]+=v2;
    a[3]+=v0*v0; a[4]+=v1*v1; a[5]+=v2*v2;
    a[6]+=v0*v1; a[7]+=v0*v2; a[8]+=v1*v2;
  }
  waveRedArr(a, 9);
  const int w = threadIdx.x >> 6, lane = threadIdx.x & 63;
  if (lane == 0){
    #pragma unroll
    for (int i = 0; i < 9; ++i) red[w][i] = a[i];
  }
  __syncthreads();
  if (threadIdx.x < 9){
    float t = 0.f;
    #pragma unroll
    for (int k = 0; k < 4; ++k) t += red[k][threadIdx.x];
    const int c = threadIdx.x;
    atomicAdd(&g_acc[(c < 3) ? (S0 + c) : (Q0 + (c - 3))], t);
  }
}

// generic BN finalize from accumulated stats (BN0, BN2, BN3)
__global__ void kfin(int dim, int soff, int qoff,
                     const float* __restrict__ g, const float* __restrict__ b, float invN){
  const int j = threadIdx.x;
  if (j >= dim) return;
  const float m = g_acc[soff+j]*invN;
  const float var = fmaxf(g_acc[qoff+j]*invN - m*m, 0.f);
  const float s = g[j]*rsqrtf(var + EPS);
  g_st[soff+j] = s;
  g_st[qoff+j] = b[j] - m*s;
}

// analytic BN1 finalize (pass-1 elimination); see R9 notes.
__global__ void kfin1(const float* __restrict__ g1, const float* __restrict__ b1bn,
                      const float* __restrict__ W1, const float* __restrict__ b1lin,
                      float invN){
  const int j = threadIdx.x;
  if (j >= 64) return;
  float m0[3], s0[3], t0[3];
  #pragma unroll
  for (int c = 0; c < 3; ++c){
    m0[c] = g_acc[S0+c]*invN;
    s0[c] = g_st[S0+c];
    t0[c] = g_st[Q0+c];
  }
  float C[3][3];
  C[0][0] = g_acc[Q0+0]*invN - m0[0]*m0[0];
  C[1][1] = g_acc[Q0+1]*invN - m0[1]*m0[1];
  C[2][2] = g_acc[Q0+2]*invN - m0[2]*m0[2];
  C[0][1] = C[1][0] = g_acc[Q0+3]*invN - m0[0]*m0[1];
  C[0][2] = C[2][0] = g_acc[Q0+4]*invN - m0[0]*m0[2];
  C[1][2] = C[2][1] = g_acc[Q0+5]*invN - m0[1]*m0[2];

  float wj[3] = {W1[0*64 + j], W1[1*64 + j], W1[2*64 + j]};
  float mean = b1lin[j];
  #pragma unroll
  for (int c = 0; c < 3; ++c) mean += (m0[c]*s0[c] + t0[c])*wj[c];
  float var = 0.f;
  #pragma unroll
  for (int a = 0; a < 3; ++a)
    #pragma unroll
    for (int b = 0; b < 3; ++b)
      var += wj[a]*s0[a]*wj[b]*s0[b]*C[a][b];
  var = fmaxf(var, 0.f);
  const float sc = g1[j]*rsqrtf(var + EPS);
  g_st[S1+j] = sc;
  g_st[Q1+j] = b1bn[j] - mean*sc;
}

// STAGE 2..3: stats for z2..z3; STAGE 4: final layer + coalesced segment-max.
// LDS liveness overlay (u16 units):
//   STAGE 2: h1 @ 0                                (8 KB)
//   STAGE 3: h2 @ 0, h1 @ 8192                     (24 KB)
//   STAGE 4: h2 @ 0, h1 @ 8192, h3 @ 8192 (over h1, h1 dead),
//            z4 (f32[64][132]) @ 0 (over h2+h3 after all reads) (48 KB peak)
template<int STAGE>
__global__ __launch_bounds__(256) void kpass(
    const float* __restrict__ x, const void* __restrict__ unq_inv_v,
    const float* __restrict__ W1, const float* __restrict__ b1,
    const float* __restrict__ W2, const float* __restrict__ b2,
    const float* __restrict__ W3, const float* __restrict__ b3,
    const float* __restrict__ W4, const float* __restrict__ b4,
    float* __restrict__ out, int N, long outSize)
{
  constexpr bool NEED_H2 = (STAGE >= 3);
  constexpr bool NEED_H3 = (STAGE >= 4);
  constexpr int BUF_U16 = (STAGE == 2) ? 4096 : (STAGE == 3) ? 12288 : 24576;
  __shared__ u16 buf[BUF_U16];
  __shared__ float bs[(STAGE <= 3) ? 256 : 1], bq[(STAGE <= 3) ? 256 : 1];
  __shared__ int seg_s[NEED_H3 ? 64 : 1];

  u16* const h1s = buf + ((STAGE >= 3) ? 8192 : 0);
  u16* const h2s = buf;                 // stages >= 3
  u16* const h3s = buf + 8192;          // stage 4 (overlays h1; h1 dead)
  float* const z4 = (float*)buf;        // stage 4 flush staging [64][132]

  const long U = g_U;
  const int inv64 = g_inv64;
  const long loEl = 3*U;
  const long hiEl = (131*U < outSize) ? 131*U : outSize;

  const int tid  = threadIdx.x;
  const int w    = tid >> 6;
  const int lane = tid & 63;

  if constexpr (STAGE <= 3){
    for (int i = tid; i < 256; i += 256){ bs[i] = 0.f; bq[i] = 0.f; }
    __syncthreads();
  }

  const int nb = (N + PTS - 1) / PTS;
  for (int b = blockIdx.x; b < nb; b += gridDim.x){
    const int p = b*PTS + lane;
    const bool valid = p < N;

    { // bn0 + layer 1: 3 -> 64 (feeds h1)
      float h0[3];
      #pragma unroll
      for (int c = 0; c < 3; ++c){
        float xv = valid ? x[(size_t)p*3 + c] : 0.f;
        h0[c] = xv*g_st[S0 + c] + g_st[Q0 + c];
      }
      const int j0u = __builtin_amdgcn_readfirstlane(w*16);
      float acc[16];
      #pragma unroll
      for (int jj = 0; jj < 16; ++jj) acc[jj] = b1[j0u + jj];
      #pragma unroll
      for (int k = 0; k < 3; ++k){
        const float* Wr = W1 + k*64 + j0u;
        #pragma unroll
        for (int jj = 0; jj < 16; ++jj) acc[jj] = fmaf(h0[k], Wr[jj], acc[jj]);
      }
      emitH(acc, lane, j0u, S1, Q1, h1s);
    }
    { // layer 2: 64 -> 128
      __syncthreads();
      #pragma unroll
      for (int c = 0; c < 2; ++c){
        const int j0 = w*32 + c*16;
        float acc[16];
        chunk16<64,128>(h1s, lane, W2, b2, j0, acc);
        if constexpr (STAGE == 2) emitStats(acc, valid, lane, j0, bs, bq);
        else emitH(acc, lane, __builtin_amdgcn_readfirstlane(j0), S2, Q2, h2s);
      }
    }
    if constexpr (NEED_H2){ // layer 3: 128 -> 256 (h3 overwrites dead h1)
      __syncthreads();
      #pragma unroll
      for (int c = 0; c < 4; ++c){
        const int j0 = w*64 + c*16;
        float acc[16];
        chunk16<128,256>(h2s, lane, W3, b3, j0, acc);
        if constexpr (STAGE == 3) emitStats(acc, valid, lane, j0, bs, bq);
        else emitH(acc, lane, __builtin_amdgcn_readfirstlane(j0), S3, Q3, h3s);
      }
    }
    if constexpr (NEED_H3){ // layer 4: 256 -> 128, staged + coalesced segment-max
      __syncthreads();  // h3 ready
      float accA[16], accB[16];
      chunk16<256,128>(h3s, lane, W4, b4, w*32,      accA);
      chunk16<256,128>(h3s, lane, W4, b4, w*32 + 16, accB);
      if (w == 0){
        long seg = -1;
        if (valid){
          if (inv64) seg = (long)((const long long*)unq_inv_v)[p];
          else       seg = (long)((const int*)unq_inv_v)[p];
        }
        seg_s[lane] = (seg >= 0 && seg < U &&
                       loEl + seg*128 + 128 <= hiEl) ? (int)seg : -1;
      }
      __syncthreads();  // all h3/h2 reads done -> z4 space free; seg_s ready
      {
        float4* dst = (float4*)&z4[lane*132 + w*32];
        dst[0] = make_float4(accA[ 0],accA[ 1],accA[ 2],accA[ 3]);
        dst[1] = make_float4(accA[ 4],accA[ 5],accA[ 6],accA[ 7]);
        dst[2] = make_float4(accA[ 8],accA[ 9],accA[10],accA[11]);
        dst[3] = make_float4(accA[12],accA[13],accA[14],accA[15]);
        dst[4] = make_float4(accB[ 0],accB[ 1],accB[ 2],accB[ 3]);
        dst[5] = make_float4(accB[ 4],accB[ 5],accB[ 6],accB[ 7]);
        dst[6] = make_float4(accB[ 8],accB[ 9],accB[10],accB[11]);
        dst[7] = make_float4(accB[12],accB[13],accB[14],accB[15]);
      }
      __syncthreads();  // z4 complete
      #pragma unroll 4
      for (int pt2 = 0; pt2 < 64; pt2 += 2){
        const int pt = pt2 + (tid >> 7);
        const int f  = tid & 127;
        const int sg = seg_s[pt];
        if (sg >= 0)
          atomicMaxF32(out + loEl + (long)sg*128 + f, z4[pt*132 + f]);
      }
    }
    __syncthreads();  // protect LDS across tile iterations
  }

  if constexpr (STAGE <= 3){
    const int dim  = (STAGE == 2) ? 128 : 256;
    const int soff = (STAGE == 2) ? S2 : S3;
    const int qoff = (STAGE == 2) ? Q2 : Q3;
    for (int j = tid; j < dim; j += 256){
      atomicAdd(&g_acc[soff + j], bs[j]);
      atomicAdd(&g_acc[qoff + j], bq[j]);
    }
  }
}

extern "C" void kernel_launch(void* const* d_in, const int* in_sizes, int n_in,
                              void* d_out, int out_size, void* d_ws, size_t ws_size,
                              hipStream_t stream)
{
  const float* x       = (const float*)d_in[0];
  const void*  unq     = d_in[2];
  const void*  unq_inv = d_in[3];
  const float* bn_g[4] = {(const float*)d_in[4], (const float*)d_in[6], (const float*)d_in[8], (const float*)d_in[10]};
  const float* bn_b[4] = {(const float*)d_in[5], (const float*)d_in[7], (const float*)d_in[9], (const float*)d_in[11]};
  const float* W1 = (const float*)d_in[12]; const float* b1 = (const float*)d_in[13];
  const float* W2 = (const float*)d_in[14]; const float* b2 = (const float*)d_in[15];
  const float* W3 = (const float*)d_in[16]; const float* b3 = (const float*)d_in[17];
  const float* W4 = (const float*)d_in[18]; const float* b4 = (const float*)d_in[19];

  const int N = in_sizes[0] / 3;
  float* out = (float*)d_out;
  const float invN = 1.0f / (float)N;
  const long outSize = (long)out_size;

  kreset<<<1, 1024, 0, stream>>>();
  ksniff_inv<<<1, 1024, 0, stream>>>((const u32*)unq_inv, (long)N);
  ksegU<<<512, 256, 0, stream>>>(unq_inv, N);
  ksetU<<<1, 64, 0, stream>>>();
  ksniff_unq<<<1, 1024, 0, stream>>>((const u32*)unq);
  kpoolinit<<<2048, 256, 0, stream>>>(out, outSize);

  kstats0<<<1024, 256, 0, stream>>>(x, N);
  kfin<<<1, 256, 0, stream>>>(3, S0, Q0, bn_g[0], bn_b[0], invN);
  kfin1<<<1, 64, 0, stream>>>(bn_g[1], bn_b[1], W1, b1, invN);

  kpass<2><<<1024, 256, 0, stream>>>(x, unq_inv, W1,b1,W2,b2,W3,b3,W4,b4, out, N, outSize);
  kfin<<<1, 256, 0, stream>>>(128, S2, Q2, bn_g[2], bn_b[2], invN);

  kpass<3><<<1024, 256, 0, stream>>>(x, unq_inv, W1,b1,W2,b2,W3,b3,W4,b4, out, N, outSize);
  kfin<<<1, 256, 0, stream>>>(256, S3, Q3, bn_g[3], bn_b[3], invN);

  kpass<4><<<768, 256, 0, stream>>>(x, unq_inv, W1,b1,W2,b2,W3,b3,W4,b4, out, N, outSize);

  kunq<<<2048, 256, 0, stream>>>(out, unq, outSize);
}

// Round 12
// 3548.331 us; speedup vs baseline: 4.2171x; 1.0318x over previous
//
#include <hip/hip_runtime.h>
#include <math.h>

typedef unsigned int u32;
typedef unsigned short u16;

#define EPS 1e-5f
#define PTS 64   // points per tile (= one wavefront)

// stats/scale-shift offsets into g_acc / g_st (floats)
#define S0 0
#define Q0 16
#define S1 32
#define Q1 96
#define S2 160
#define Q2 288
#define S3 416
#define Q3 672

__device__ float g_acc[1024];  // sums (S*), sum-of-squares (Q*), cross-terms (Q0+3..5)
__device__ float g_st[1024];   // per-feature scale (at S*) and shift (at Q*)
__device__ int   g_is64;       // 1 if unq buffer is int64
__device__ int   g_inv64;      // 1 if unq_inv buffer is int64
__device__ int   g_umax;       // max(unq_inv)
__device__ long  g_U;          // segment count = g_umax + 1

__device__ __forceinline__ float bf2f(u16 b){ return __uint_as_float(((u32)b) << 16); }
__device__ __forceinline__ u16 f2bf(float f){
  u32 u = __float_as_uint(f);
  return (u16)((u + 0x7fffu + ((u >> 16) & 1u)) >> 16);  // RNE
}

// float atomic max via sign-split HW atomics; requires init to -inf.
__device__ __forceinline__ void atomicMaxF32(float* addr, float v){
  if (v == 0.f) v = 0.f;            // canonicalize -0.0 -> +0.0
  if (v >= 0.f) atomicMax((int*)addr, __float_as_int(v));
  else          atomicMin((u32*)addr, __float_as_uint(v));
}

__device__ __forceinline__ void waveRedArr(float* v, int n){
  #pragma unroll
  for (int off = 32; off > 0; off >>= 1)
    for (int i = 0; i < n; ++i) v[i] += __shfl_xor(v[i], off, 64);
}

// 16 outputs; h from LDS bf16 tile hsrc[FIN][PTS]; weights via wave-uniform
// (readfirstlane-forced) scalar addressing -> s_load.
template<int FIN, int FOUT>
__device__ __forceinline__ void chunk16(const u16* hsrc, int lane,
    const float* __restrict__ W, const float* __restrict__ bias,
    int j0, float acc[16])
{
  const int j0u = __builtin_amdgcn_readfirstlane(j0);
  #pragma unroll
  for (int jj = 0; jj < 16; ++jj) acc[jj] = bias[j0u + jj];
  #pragma unroll 4
  for (int k = 0; k < FIN; ++k){
    const float hk = bf2f(hsrc[k*PTS + lane]);
    const float* Wr = W + (long)k*FOUT + j0u;
    #pragma unroll
    for (int jj = 0; jj < 16; ++jj) acc[jj] = fmaf(hk, Wr[jj], acc[jj]);
  }
}

__device__ __forceinline__ void emitStats(float acc[16], bool valid, int lane, int j0,
                                          float* bs, float* bq){
  #pragma unroll
  for (int jj = 0; jj < 16; ++jj){
    float v = valid ? acc[jj] : 0.f;
    float sq[2] = {v, v*v};
    waveRedArr(sq, 2);
    if (lane == 0){ atomicAdd(&bs[j0+jj], sq[0]); atomicAdd(&bq[j0+jj], sq[1]); }
  }
}
__device__ __forceinline__ void emitH(float acc[16], int lane, int j0u, int soff, int qoff, u16* hdst){
  #pragma unroll
  for (int jj = 0; jj < 16; ++jj){
    float z = fmaxf(acc[jj]*g_st[soff+j0u+jj] + g_st[qoff+j0u+jj], 0.f);
    hdst[(j0u+jj)*PTS + lane] = f2bf(z);
  }
}

__global__ void kreset(){
  if (threadIdx.x == 0) g_umax = 0;
  for (int i = threadIdx.x; i < 1024; i += blockDim.x) g_acc[i] = 0.f;
}

// int64 data (values < 2^31): all odd 32-bit words are zero. int32: not.
__global__ void ksniff_inv(const u32* __restrict__ w, long nwords){
  __shared__ int any;
  if (threadIdx.x == 0) any = 0;
  __syncthreads();
  for (long i = 2L*threadIdx.x + 1; i < nwords; i += 2L*blockDim.x){
    if (w[i] != 0u){ any = 1; break; }
  }
  __syncthreads();
  if (threadIdx.x == 0) g_inv64 = (any == 0) ? 1 : 0;
}

__global__ __launch_bounds__(256) void ksegU(const void* __restrict__ invv, int N){
  const int inv64 = g_inv64;
  int m = 0;
  const int stride = gridDim.x*blockDim.x;
  if (inv64){
    const long long* q = (const long long*)invv;
    for (int i = blockIdx.x*blockDim.x + threadIdx.x; i < N; i += stride)
      m = max(m, (int)q[i]);
  } else {
    const int* q = (const int*)invv;
    for (int i = blockIdx.x*blockDim.x + threadIdx.x; i < N; i += stride)
      m = max(m, q[i]);
  }
  #pragma unroll
  for (int off = 32; off > 0; off >>= 1) m = max(m, __shfl_xor(m, off, 64));
  if ((threadIdx.x & 63) == 0) atomicMax(&g_umax, m);
}

__global__ void ksetU(){
  if (threadIdx.x == 0) g_U = (long)g_umax + 1;
}

__global__ void ksniff_unq(const u32* __restrict__ w){
  const long nwords = 3L*g_U;
  __shared__ int any;
  if (threadIdx.x == 0) any = 0;
  __syncthreads();
  for (long i = 2L*threadIdx.x + 1; i < nwords; i += 2L*blockDim.x){
    if (w[i] != 0u){ any = 1; break; }
  }
  __syncthreads();
  if (threadIdx.x == 0) g_is64 = (any == 0) ? 1 : 0;
}

// init pooled region [3U, 131U) to -inf (f32)
__global__ void kpoolinit(float* __restrict__ out, long outSize){
  const long U = g_U;
  const long lo = 3*U;
  const long hi = (131*U < outSize) ? 131*U : outSize;
  const long i0 = (long)blockIdx.x*blockDim.x + threadIdx.x;
  const long stride = (long)gridDim.x*blockDim.x;
  for (long i = lo + i0; i < hi; i += stride) out[i] = -INFINITY;
}

// unq coords into [0, 3U) as f32
__global__ void kunq(float* __restrict__ out, const void* __restrict__ unqv, long outSize){
  const long U = g_U;
  const long n = (3*U < outSize) ? 3*U : outSize;
  const long i0 = (long)blockIdx.x*blockDim.x + threadIdx.x;
  const long stride = (long)gridDim.x*blockDim.x;
  if (g_is64){
    const long long* uq = (const long long*)unqv;
    for (long i = i0; i < n; i += stride) out[i] = (float)uq[i];
  } else {
    const int* uq = (const int*)unqv;
    for (long i = i0; i < n; i += stride) out[i] = (float)uq[i];
  }
}

// stats0: 9 sums over x: Σx (3), Σx² (3), Σxy,Σxz,Σyz (3)
__global__ __launch_bounds__(256) void kstats0(const float* __restrict__ x, int N){
  __shared__ float red[4][9];
  float a[9];
  #pragma unroll
  for (int i = 0; i < 9; ++i) a[i] = 0.f;
  const int stride = gridDim.x*blockDim.x;
  for (int p = blockIdx.x*blockDim.x + threadIdx.x; p < N; p += stride){
    float v0 = x[(size_t)p*3 + 0], v1 = x[(size_t)p*3 + 1], v2 = x[(size_t)p*3 + 2];
    a[0]+=v0; a[1]+=v1; a[2]+=v2;
    a[3]+=v0*v0; a[4]+=v1*v1; a[5]+=v2*v2;
    a[6]+=v0*v1; a[7]+=v0*v2; a[8]+=v1*v2;
  }
  waveRedArr(a, 9);
  const int w = threadIdx.x >> 6, lane = threadIdx.x & 63;
  if (lane == 0){
    #pragma unroll
    for (int i = 0; i < 9; ++i) red[w][i] = a[i];
  }
  __syncthreads();
  if (threadIdx.x < 9){
    float t = 0.f;
    #pragma unroll
    for (int k = 0; k < 4; ++k) t += red[k][threadIdx.x];
    const int c = threadIdx.x;
    atomicAdd(&g_acc[(c < 3) ? (S0 + c) : (Q0 + (c - 3))], t);
  }
}

// generic BN finalize from accumulated stats (BN0, BN2, BN3)
__global__ void kfin(int dim, int soff, int qoff,
                     const float* __restrict__ g, const float* __restrict__ b, float invN){
  const int j = threadIdx.x;
  if (j >= dim) return;
  const float m = g_acc[soff+j]*invN;
  const float var = fmaxf(g_acc[qoff+j]*invN - m*m, 0.f);
  const float s = g[j]*rsqrtf(var + EPS);
  g_st[soff+j] = s;
  g_st[qoff+j] = b[j] - m*s;
}

// analytic BN1 finalize (pass-1 elimination); see R9 notes.
__global__ void kfin1(const float* __restrict__ g1, const float* __restrict__ b1bn,
                      const float* __restrict__ W1, const float* __restrict__ b1lin,
                      float invN){
  const int j = threadIdx.x;
  if (j >= 64) return;
  float m0[3], s0[3], t0[3];
  #pragma unroll
  for (int c = 0; c < 3; ++c){
    m0[c] = g_acc[S0+c]*invN;
    s0[c] = g_st[S0+c];
    t0[c] = g_st[Q0+c];
  }
  float C[3][3];
  C[0][0] = g_acc[Q0+0]*invN - m0[0]*m0[0];
  C[1][1] = g_acc[Q0+1]*invN - m0[1]*m0[1];
  C[2][2] = g_acc[Q0+2]*invN - m0[2]*m0[2];
  C[0][1] = C[1][0] = g_acc[Q0+3]*invN - m0[0]*m0[1];
  C[0][2] = C[2][0] = g_acc[Q0+4]*invN - m0[0]*m0[2];
  C[1][2] = C[2][1] = g_acc[Q0+5]*invN - m0[1]*m0[2];

  float wj[3] = {W1[0*64 + j], W1[1*64 + j], W1[2*64 + j]};
  float mean = b1lin[j];
  #pragma unroll
  for (int c = 0; c < 3; ++c) mean += (m0[c]*s0[c] + t0[c])*wj[c];
  float var = 0.f;
  #pragma unroll
  for (int a = 0; a < 3; ++a)
    #pragma unroll
    for (int b = 0; b < 3; ++b)
      var += wj[a]*s0[a]*wj[b]*s0[b]*C[a][b];
  var = fmaxf(var, 0.f);
  const float sc = g1[j]*rsqrtf(var + EPS);
  g_st[S1+j] = sc;
  g_st[Q1+j] = b1bn[j] - mean*sc;
}

// STAGE 2..3: stats for z2..z3; STAGE 4: final layer + coalesced segment-max.
// WSMODE: 0 = none; 1 (STAGE 3) = store pre-BN z3 f32 to ws[m*N+p];
//         2 (STAGE 4) = load z3 from ws, skip L1-L3 recompute.
// LDS overlay (u16 units):
//   STAGE 2:            h1 @ 0                     (8 KB)
//   STAGE 3:            h2 @ 0, h1 @ 8192          (24 KB)
//   STAGE 4, WSMODE 0:  h2 @ 0, h1/h3 @ 8192, z4 over all (48 KB)
//   STAGE 4, WSMODE 2:  h3 @ 0, z4 over h3         (33.8 KB -> 4 blocks/CU)
template<int STAGE, int WSMODE>
__global__ __launch_bounds__(256) void kpass(
    const float* __restrict__ x, const void* __restrict__ unq_inv_v,
    const float* __restrict__ W1, const float* __restrict__ b1,
    const float* __restrict__ W2, const float* __restrict__ b2,
    const float* __restrict__ W3, const float* __restrict__ b3,
    const float* __restrict__ W4, const float* __restrict__ b4,
    float* __restrict__ z3ws, float* __restrict__ out, int N, long outSize)
{
  constexpr bool RECOMP  = (WSMODE != 2);
  constexpr bool NEED_H2 = (STAGE >= 3) && RECOMP;
  constexpr bool NEED_H3 = (STAGE >= 4);
  constexpr int BUF_U16 =
      (STAGE == 2) ? 4096 :
      (STAGE == 3) ? 12288 :
      (WSMODE == 2) ? 16896 : 24576;
  __shared__ u16 buf[BUF_U16];
  __shared__ float bs[(STAGE <= 3) ? 256 : 1], bq[(STAGE <= 3) ? 256 : 1];
  __shared__ int seg_s[NEED_H3 ? 64 : 1];

  u16* const h1s = buf + ((STAGE >= 3 && RECOMP) ? 8192 : 0);
  u16* const h2s = buf;                                    // stages >= 3, recompute
  u16* const h3s = RECOMP ? (buf + 8192) : buf;            // stage 4
  float* const z4 = (float*)buf;                           // stage 4 flush staging [64][132]

  const long U = g_U;
  const int inv64 = g_inv64;
  const long loEl = 3*U;
  const long hiEl = (131*U < outSize) ? 131*U : outSize;

  const int tid  = threadIdx.x;
  const int w    = tid >> 6;
  const int lane = tid & 63;

  if constexpr (STAGE <= 3){
    for (int i = tid; i < 256; i += 256){ bs[i] = 0.f; bq[i] = 0.f; }
    __syncthreads();
  }

  const int nb = (N + PTS - 1) / PTS;
  for (int b = blockIdx.x; b < nb; b += gridDim.x){
    const int p = b*PTS + lane;
    const bool valid = p < N;

    if constexpr (RECOMP){
      { // bn0 + layer 1: 3 -> 64 (feeds h1)
        float h0[3];
        #pragma unroll
        for (int c = 0; c < 3; ++c){
          float xv = valid ? x[(size_t)p*3 + c] : 0.f;
          h0[c] = xv*g_st[S0 + c] + g_st[Q0 + c];
        }
        const int j0u = __builtin_amdgcn_readfirstlane(w*16);
        float acc[16];
        #pragma unroll
        for (int jj = 0; jj < 16; ++jj) acc[jj] = b1[j0u + jj];
        #pragma unroll
        for (int k = 0; k < 3; ++k){
          const float* Wr = W1 + k*64 + j0u;
          #pragma unroll
          for (int jj = 0; jj < 16; ++jj) acc[jj] = fmaf(h0[k], Wr[jj], acc[jj]);
        }
        emitH(acc, lane, j0u, S1, Q1, h1s);
      }
      { // layer 2: 64 -> 128
        __syncthreads();
        #pragma unroll
        for (int c = 0; c < 2; ++c){
          const int j0 = w*32 + c*16;
          float acc[16];
          chunk16<64,128>(h1s, lane, W2, b2, j0, acc);
          if constexpr (STAGE == 2) emitStats(acc, valid, lane, j0, bs, bq);
          else emitH(acc, lane, __builtin_amdgcn_readfirstlane(j0), S2, Q2, h2s);
        }
      }
    }
    if constexpr (NEED_H2){ // layer 3: 128 -> 256 (h3 overwrites dead h1)
      __syncthreads();
      #pragma unroll
      for (int c = 0; c < 4; ++c){
        const int j0 = w*64 + c*16;
        float acc[16];
        chunk16<128,256>(h2s, lane, W3, b3, j0, acc);
        if constexpr (STAGE == 3){
          emitStats(acc, valid, lane, j0, bs, bq);
          if constexpr (WSMODE == 1){
            if (valid){
              #pragma unroll
              for (int jj = 0; jj < 16; ++jj)
                z3ws[(size_t)(j0 + jj)*N + p] = acc[jj];   // coalesced f32 store
            }
          }
        }
        else emitH(acc, lane, __builtin_amdgcn_readfirstlane(j0), S3, Q3, h3s);
      }
    }
    if constexpr (STAGE >= 4 && WSMODE == 2){ // load z3, apply bn3+relu -> h3
      const int j0u = __builtin_amdgcn_readfirstlane(w*64);
      #pragma unroll 8
      for (int mm = 0; mm < 64; ++mm){
        const int m = j0u + mm;
        float z = valid ? z3ws[(size_t)m*N + p] : 0.f;
        z = fmaxf(z*g_st[S3 + m] + g_st[Q3 + m], 0.f);
        h3s[m*PTS + lane] = f2bf(z);
      }
    }
    if constexpr (NEED_H3){ // layer 4: 256 -> 128, staged + coalesced segment-max
      __syncthreads();  // h3 ready
      float accA[16], accB[16];
      chunk16<256,128>(h3s, lane, W4, b4, w*32,      accA);
      chunk16<256,128>(h3s, lane, W4, b4, w*32 + 16, accB);
      if (w == 0){
        long seg = -1;
        if (valid){
          if (inv64) seg = (long)((const long long*)unq_inv_v)[p];
          else       seg = (long)((const int*)unq_inv_v)[p];
        }
        seg_s[lane] = (seg >= 0 && seg < U &&
                       loEl + seg*128 + 128 <= hiEl) ? (int)seg : -1;
      }
      __syncthreads();  // all LDS reads done -> z4 space free; seg_s ready
      {
        float4* dst = (float4*)&z4[lane*132 + w*32];
        dst[0] = make_float4(accA[ 0],accA[ 1],accA[ 2],accA[ 3]);
        dst[1] = make_float4(accA[ 4],accA[ 5],accA[ 6],accA[ 7]);
        dst[2] = make_float4(accA[ 8],accA[ 9],accA[10],accA[11]);
        dst[3] = make_float4(accA[12],accA[13],accA[14],accA[15]);
        dst[4] = make_float4(accB[ 0],accB[ 1],accB[ 2],accB[ 3]);
        dst[5] = make_float4(accB[ 4],accB[ 5],accB[ 6],accB[ 7]);
        dst[6] = make_float4(accB[ 8],accB[ 9],accB[10],accB[11]);
        dst[7] = make_float4(accB[12],accB[13],accB[14],accB[15]);
      }
      __syncthreads();  // z4 complete
      #pragma unroll 4
      for (int pt2 = 0; pt2 < 64; pt2 += 2){
        const int pt = pt2 + (tid >> 7);
        const int f  = tid & 127;
        const int sg = seg_s[pt];
        if (sg >= 0)
          atomicMaxF32(out + loEl + (long)sg*128 + f, z4[pt*132 + f]);
      }
    }
    __syncthreads();  // protect LDS across tile iterations
  }

  if constexpr (STAGE <= 3){
    const int dim  = (STAGE == 2) ? 128 : 256;
    const int soff = (STAGE == 2) ? S2 : S3;
    const int qoff = (STAGE == 2) ? S2 == S2 ? ((STAGE == 2) ? Q2 : Q3) : Q3 : Q3;  // keep simple below
    const int qo   = (STAGE == 2) ? Q2 : Q3;
    for (int j = tid; j < dim; j += 256){
      atomicAdd(&g_acc[soff + j], bs[j]);
      atomicAdd(&g_acc[qo + j], bq[j]);
    }
  }
}

extern "C" void kernel_launch(void* const* d_in, const int* in_sizes, int n_in,
                              void* d_out, int out_size, void* d_ws, size_t ws_size,
                              hipStream_t stream)
{
  const float* x       = (const float*)d_in[0];
  const void*  unq     = d_in[2];
  const void*  unq_inv = d_in[3];
  const float* bn_g[4] = {(const float*)d_in[4], (const float*)d_in[6], (const float*)d_in[8], (const float*)d_in[10]};
  const float* bn_b[4] = {(const float*)d_in[5], (const float*)d_in[7], (const float*)d_in[9], (const float*)d_in[11]};
  const float* W1 = (const float*)d_in[12]; const float* b1 = (const float*)d_in[13];
  const float* W2 = (const float*)d_in[14]; const float* b2 = (const float*)d_in[15];
  const float* W3 = (const float*)d_in[16]; const float* b3 = (const float*)d_in[17];
  const float* W4 = (const float*)d_in[18]; const float* b4 = (const float*)d_in[19];

  const int N = in_sizes[0] / 3;
  float* out = (float*)d_out;
  float* z3ws = (float*)d_ws;
  const float invN = 1.0f / (float)N;
  const long outSize = (long)out_size;
  const bool useWs = (ws_size >= (size_t)N * 256 * sizeof(float));

  kreset<<<1, 1024, 0, stream>>>();
  ksniff_inv<<<1, 1024, 0, stream>>>((const u32*)unq_inv, (long)N);
  ksegU<<<512, 256, 0, stream>>>(unq_inv, N);
  ksetU<<<1, 64, 0, stream>>>();
  ksniff_unq<<<1, 1024, 0, stream>>>((const u32*)unq);
  kpoolinit<<<2048, 256, 0, stream>>>(out, outSize);

  kstats0<<<1024, 256, 0, stream>>>(x, N);
  kfin<<<1, 256, 0, stream>>>(3, S0, Q0, bn_g[0], bn_b[0], invN);
  kfin1<<<1, 64, 0, stream>>>(bn_g[1], bn_b[1], W1, b1, invN);

  kpass<2,0><<<1792, 256, 0, stream>>>(x, unq_inv, W1,b1,W2,b2,W3,b3,W4,b4, z3ws, out, N, outSize);
  kfin<<<1, 256, 0, stream>>>(128, S2, Q2, bn_g[2], bn_b[2], invN);

  if (useWs){
    kpass<3,1><<<1536, 256, 0, stream>>>(x, unq_inv, W1,b1,W2,b2,W3,b3,W4,b4, z3ws, out, N, outSize);
    kfin<<<1, 256, 0, stream>>>(256, S3, Q3, bn_g[3], bn_b[3], invN);
    kpass<4,2><<<1024, 256, 0, stream>>>(x, unq_inv, W1,b1,W2,b2,W3,b3,W4,b4, z3ws, out, N, outSize);
  } else {
    kpass<3,0><<<1536, 256, 0, stream>>>(x, unq_inv, W1,b1,W2,b2,W3,b3,W4,b4, z3ws, out, N, outSize);
    kfin<<<1, 256, 0, stream>>>(256, S3, Q3, bn_g[3], bn_b[3], invN);
    kpass<4,0><<<768, 256, 0, stream>>>(x, unq_inv, W1,b1,W2,b2,W3,b3,W4,b4, z3ws, out, N, outSize);
  }

  kunq<<<2048, 256, 0, stream>>>(out, unq, outSize);
}